// Round 5
// baseline (417.912 us; speedup 1.0000x reference)
//
#include <hip/hip_runtime.h>
#include <math.h>

constexpr int NN  = 50000;
constexpr int NE  = 800000;
constexpr int NNP = 50048;             // padded rows = 391 * 128
constexpr int NB  = (NN + 255) / 256;  // scan blocks

typedef __bf16 bf16x8 __attribute__((ext_vector_type(8)));
typedef float  f32x4  __attribute__((ext_vector_type(4)));
typedef __attribute__((address_space(1))) unsigned int as1_uint;
typedef __attribute__((address_space(3))) unsigned int as3_uint;

__device__ __forceinline__ unsigned short f2bf(float x) {  // RNE fp32->bf16 bits
    unsigned int u = __float_as_uint(x);
    return (unsigned short)((u + 0x7FFFu + ((u >> 16) & 1u)) >> 16);
}
__device__ __forceinline__ float bf2f(unsigned short h) {
    return __uint_as_float(((unsigned int)h) << 16);
}

__device__ __forceinline__ void gload16(const unsigned short* g, unsigned short* l) {
    __builtin_amdgcn_global_load_lds((const as1_uint*)(unsigned long long)g,
                                     (as3_uint*)(unsigned long long)l, 16, 0, 0);
}

// ---------------- CSR build ----------------
__global__ void k_count(const int* __restrict__ dst, int* __restrict__ cnt) {
    int i = blockIdx.x * blockDim.x + threadIdx.x;
    if (i < NE) atomicAdd(&cnt[dst[i]], 1);
}

__global__ void k_dinv(const int* __restrict__ cnt, float* __restrict__ dinv) {
    int i = blockIdx.x * blockDim.x + threadIdx.x;
    if (i < NN) dinv[i] = rsqrtf(fmaxf((float)cnt[i], 1.0f));
}

__global__ void k_bsum(const int* __restrict__ cnt, int* __restrict__ bsum) {
    int i = blockIdx.x * 256 + threadIdx.x;
    int v = (i < NN) ? cnt[i] : 0;
#pragma unroll
    for (int off = 32; off; off >>= 1) v += __shfl_down(v, off, 64);
    __shared__ int tmp[4];
    if ((threadIdx.x & 63) == 0) tmp[threadIdx.x >> 6] = v;
    __syncthreads();
    if (threadIdx.x == 0) bsum[blockIdx.x] = tmp[0] + tmp[1] + tmp[2] + tmp[3];
}

__global__ void k_scan_bsum(const int* __restrict__ bsum, int* __restrict__ boff) {
    __shared__ int s[256];
    int t = threadIdx.x;
    int v = (t < NB) ? bsum[t] : 0;
    s[t] = v;
    __syncthreads();
    for (int off = 1; off < 256; off <<= 1) {
        int u = (t >= off) ? s[t - off] : 0;
        __syncthreads();
        s[t] += u;
        __syncthreads();
    }
    if (t < NB) boff[t] = s[t] - v;
}

__global__ void k_scan_block(const int* __restrict__ cnt, const int* __restrict__ boff,
                             int* __restrict__ rowoff) {
    __shared__ int s[256];
    int t = threadIdx.x;
    int i = blockIdx.x * 256 + t;
    int v = (i < NN) ? cnt[i] : 0;
    s[t] = v;
    __syncthreads();
    for (int off = 1; off < 256; off <<= 1) {
        int u = (t >= off) ? s[t - off] : 0;
        __syncthreads();
        s[t] += u;
        __syncthreads();
    }
    if (i < NN) rowoff[i] = boff[blockIdx.x] + s[t] - v;
}

__global__ void k_fill(const int* __restrict__ src, const int* __restrict__ dst,
                       const int* __restrict__ rowoff, int* __restrict__ cursor,
                       int* __restrict__ eidx) {
    int e = blockIdx.x * blockDim.x + threadIdx.x;
    if (e < NE) {
        int d = dst[e];
        int p = atomicAdd(&cursor[d], 1);
        eidx[rowoff[d] + p] = src[e];
    }
}

// ---------------- column-blocked low_conv gather ----------------
// H layout: [4 blocks][NNP][32] bf16 (hi and lo arrays). Per b-slice working set
// = 3.2 MB -> per-XCD L2 resident. Wave = 1 node; lanes = 2 edges x 32 cols.
__global__ __launch_bounds__(256) void k_gather_blk(
    const unsigned short* __restrict__ HH, const unsigned short* __restrict__ HL,
    const float* __restrict__ dinv, const int* __restrict__ rowoff,
    const int* __restrict__ cnt, const int* __restrict__ eidx,
    unsigned short* __restrict__ OH, unsigned short* __restrict__ OL)
{
    int node = blockIdx.x * 4 + (threadIdx.x >> 6);
    int lane = threadIdx.x & 63;
    int c = lane & 31, e = lane >> 5;
    size_t bb = (size_t)blockIdx.y * ((size_t)NNP * 32);
    if (node >= NN) {   // zero pad rows
        if (e == 0) {
            size_t o = bb + (size_t)node * 32 + c;
            OH[o] = 0; OL[o] = 0;
        }
        return;
    }
    int beg = rowoff[node];
    int n = cnt[node];
    float a0 = 0.f, a1 = 0.f;
    int j = e;
    for (; j + 2 < n; j += 4) {   // this half-wave handles edges j, j+2
        int sA = eidx[beg + j];
        int sB = eidx[beg + j + 2];
        float vA = bf2f(HH[bb + (size_t)sA * 32 + c]);
        float vB = bf2f(HH[bb + (size_t)sB * 32 + c]);
        a0 = fmaf(vA, dinv[sA], a0);
        a1 = fmaf(vB, dinv[sB], a1);
    }
    if (j < n) {
        int sA = eidx[beg + j];
        a0 = fmaf(bf2f(HH[bb + (size_t)sA * 32 + c]), dinv[sA], a0);
    }
    float acc = a0 + a1;
    acc += __shfl_down(acc, 32);   // combine the two edge-halves (same c)
    if (e == 0) {
        size_t o = bb + (size_t)node * 32 + c;
        float self = bf2f(HH[o]) + bf2f(HL[o]);
        float h = fmaf(acc, dinv[node], self);
        unsigned short hi = f2bf(h);
        OH[o] = hi;
        OL[o] = f2bf(h - bf2f(hi));
    }
}

// ---------------- small fp32 GEMM on weights: W1p[128][256] = W1 @ Wp1 ----------------
__global__ void k_mm128(const float* __restrict__ W1, const float* __restrict__ Wp1,
                        float* __restrict__ W1p) {
    int i = blockIdx.x;    // 128
    int j = threadIdx.x;   // 256
    float s = 0.f;
    for (int k = 0; k < 128; ++k) s = fmaf(W1[i * 128 + k], Wp1[k * 256 + j], s);
    W1p[i * 256 + j] = s;
}

// ---------------- weight transpose + hi/lo split: W[K][N] -> Wt[N][K] ----------------
__global__ void k_wsplit(const float* __restrict__ W, unsigned short* __restrict__ th,
                         unsigned short* __restrict__ tl, int K, int N) {
    int idx = blockIdx.x * blockDim.x + threadIdx.x;
    if (idx < K * N) {
        int k = idx / N, n = idx - k * N;
        float a = W[idx];
        unsigned short hi = f2bf(a);
        float lo = a - bf2f(hi);
        th[(size_t)n * K + k] = hi;
        tl[(size_t)n * K + k] = f2bf(lo);
    }
}

// ---------------- BN prep: stats -> scale/shift ----------------
__global__ void k_bnprep(const float* __restrict__ stats, const float* __restrict__ gamma,
                         const float* __restrict__ beta, float* __restrict__ scale,
                         float* __restrict__ shift) {
    int c = threadIdx.x;
    float mu  = stats[c] * (1.0f / NN);
    float var = stats[256 + c] * (1.0f / NN) - mu * mu;
    float s = gamma[c] * rsqrtf(var + 1e-5f);
    scale[c] = s;
    shift[c] = beta[c] - mu * s;
}

// ---------------- split-precision MFMA GEMM ----------------
// AMODE: 0 = bf16 hi(/lo) via global_load_lds; 1 = fp32 reg-staged -> bf16;
//        2 = fp32 reg-staged with BN(scale/shift)+ReLU -> bf16.
// ABLK: A stored column-blocked [K/32][NNP][32]. OBLK: emit hi/lo bf16 blocked output.
// STATS: accumulate per-column sum/sumsq of C into statsOut (BN training stats).
template <int K, int NCOLS, bool BIAS, bool ALO, int AMODE, bool ABLK, bool OBLK, bool STATS>
__global__ __launch_bounds__(512) void k_mfma(
    const unsigned short* __restrict__ AH, const unsigned short* __restrict__ AL,
    const float* __restrict__ Af,
    const unsigned short* __restrict__ BH, const unsigned short* __restrict__ BL,
    const float* __restrict__ bias,
    const float* __restrict__ bnscl, const float* __restrict__ bnshf,
    float* __restrict__ C, unsigned short* __restrict__ OHs, unsigned short* __restrict__ OLs,
    float* __restrict__ statsOut)
{
    __shared__ __align__(16) unsigned short lds[4 * 4096];
    unsigned short* ldsAH = lds;
    unsigned short* ldsAL = lds + 4096;
    unsigned short* ldsBH = lds + 8192;
    unsigned short* ldsBL = lds + 12288;

    const int tid  = threadIdx.x;
    const int lane = tid & 63;
    const int wid  = tid >> 6;
    const int wm   = wid >> 1;
    const int wn   = wid & 1;
    const int row0 = blockIdx.x * 128;
    const int col0 = blockIdx.y * 128;

    const int srow  = tid >> 2;
    const int skg   = tid & 3;
    const int skswz = skg ^ ((srow >> 1) & 3);  // inverse swizzle on SOURCE
    const size_t aSrc     = (size_t)(row0 + srow) * K + skswz * 8;       // flat A
    const size_t aBlkBase = (size_t)(row0 + srow) * 32 + skswz * 8;      // blocked A
    const size_t bSrc     = (size_t)(col0 + srow) * K + skswz * 8;

    const int frow = lane & 15;
    const int fkg  = lane >> 4;

    f32x4 acc[2][4] = {};

    for (int k0 = 0; k0 < K; k0 += 32) {
        if constexpr (AMODE == 1) {
            float4 f0, f1;
            if (row0 + srow < NN) {
                const float* ap = Af + aSrc + k0;
                f0 = *reinterpret_cast<const float4*>(ap);
                f1 = *reinterpret_cast<const float4*>(ap + 4);
            } else {
                f0 = make_float4(0.f, 0.f, 0.f, 0.f);
                f1 = f0;
            }
            uint4 w;
            w.x = (unsigned)f2bf(f0.x) | ((unsigned)f2bf(f0.y) << 16);
            w.y = (unsigned)f2bf(f0.z) | ((unsigned)f2bf(f0.w) << 16);
            w.z = (unsigned)f2bf(f1.x) | ((unsigned)f2bf(f1.y) << 16);
            w.w = (unsigned)f2bf(f1.z) | ((unsigned)f2bf(f1.w) << 16);
            *reinterpret_cast<uint4*>(&ldsAH[tid * 8]) = w;
        } else if constexpr (AMODE == 2) {
            float4 f0, f1;
            if (row0 + srow < NN) {
                const float* ap = Af + aSrc + k0;
                f0 = *reinterpret_cast<const float4*>(ap);
                f1 = *reinterpret_cast<const float4*>(ap + 4);
            } else {
                f0 = make_float4(0.f, 0.f, 0.f, 0.f);
                f1 = f0;
            }
            int kc = k0 + skswz * 8;
            float4 s0 = *reinterpret_cast<const float4*>(&bnscl[kc]);
            float4 s1 = *reinterpret_cast<const float4*>(&bnscl[kc + 4]);
            float4 t0 = *reinterpret_cast<const float4*>(&bnshf[kc]);
            float4 t1 = *reinterpret_cast<const float4*>(&bnshf[kc + 4]);
            float v0 = fmaxf(fmaf(f0.x, s0.x, t0.x), 0.f);
            float v1 = fmaxf(fmaf(f0.y, s0.y, t0.y), 0.f);
            float v2 = fmaxf(fmaf(f0.z, s0.z, t0.z), 0.f);
            float v3 = fmaxf(fmaf(f0.w, s0.w, t0.w), 0.f);
            float v4 = fmaxf(fmaf(f1.x, s1.x, t1.x), 0.f);
            float v5 = fmaxf(fmaf(f1.y, s1.y, t1.y), 0.f);
            float v6 = fmaxf(fmaf(f1.z, s1.z, t1.z), 0.f);
            float v7 = fmaxf(fmaf(f1.w, s1.w, t1.w), 0.f);
            uint4 w;
            w.x = (unsigned)f2bf(v0) | ((unsigned)f2bf(v1) << 16);
            w.y = (unsigned)f2bf(v2) | ((unsigned)f2bf(v3) << 16);
            w.z = (unsigned)f2bf(v4) | ((unsigned)f2bf(v5) << 16);
            w.w = (unsigned)f2bf(v6) | ((unsigned)f2bf(v7) << 16);
            *reinterpret_cast<uint4*>(&ldsAH[tid * 8]) = w;
        } else {
            if constexpr (ABLK) {
                size_t aOff = (size_t)(k0 >> 5) * ((size_t)NNP * 32) + aBlkBase;
                gload16(AH + aOff, ldsAH + tid * 8);
                if constexpr (ALO) gload16(AL + aOff, ldsAL + tid * 8);
            } else {
                gload16(AH + aSrc + k0, ldsAH + tid * 8);
                if constexpr (ALO) gload16(AL + aSrc + k0, ldsAL + tid * 8);
            }
        }
        gload16(BH + bSrc + k0, ldsBH + tid * 8);
        gload16(BL + bSrc + k0, ldsBL + tid * 8);
        __syncthreads();

        bf16x8 a_h[2], a_l[2], b_h[4], b_l[4];
#pragma unroll
        for (int mi = 0; mi < 2; ++mi) {
            int ar  = wm * 32 + mi * 16 + frow;
            int idx = ar * 32 + ((fkg ^ ((ar >> 1) & 3)) * 8);
            a_h[mi] = *reinterpret_cast<const bf16x8*>(&ldsAH[idx]);
            if constexpr (ALO) a_l[mi] = *reinterpret_cast<const bf16x8*>(&ldsAL[idx]);
        }
#pragma unroll
        for (int ni = 0; ni < 4; ++ni) {
            int bc  = wn * 64 + ni * 16 + frow;
            int idx = bc * 32 + ((fkg ^ ((bc >> 1) & 3)) * 8);
            b_h[ni] = *reinterpret_cast<const bf16x8*>(&ldsBH[idx]);
            b_l[ni] = *reinterpret_cast<const bf16x8*>(&ldsBL[idx]);
        }
#pragma unroll
        for (int mi = 0; mi < 2; ++mi)
#pragma unroll
            for (int ni = 0; ni < 4; ++ni) {
                acc[mi][ni] = __builtin_amdgcn_mfma_f32_16x16x32_bf16(a_h[mi], b_h[ni], acc[mi][ni], 0, 0, 0);
                acc[mi][ni] = __builtin_amdgcn_mfma_f32_16x16x32_bf16(a_h[mi], b_l[ni], acc[mi][ni], 0, 0, 0);
                if constexpr (ALO)
                    acc[mi][ni] = __builtin_amdgcn_mfma_f32_16x16x32_bf16(a_l[mi], b_h[ni], acc[mi][ni], 0, 0, 0);
            }
        __syncthreads();
    }

    float psum[4] = {0.f, 0.f, 0.f, 0.f}, psq[4] = {0.f, 0.f, 0.f, 0.f};
#pragma unroll
    for (int mi = 0; mi < 2; ++mi) {
        int rbase = row0 + wm * 32 + mi * 16 + (lane >> 4) * 4;
#pragma unroll
        for (int ni = 0; ni < 4; ++ni) {
            int col = col0 + wn * 64 + ni * 16 + (lane & 15);
            float b = BIAS ? bias[col] : 0.f;
#pragma unroll
            for (int r = 0; r < 4; ++r) {
                int row = rbase + r;
                if (row < NN) {
                    float v = acc[mi][ni][r] + b;
                    if constexpr (STATS) { psum[ni] += v; psq[ni] = fmaf(v, v, psq[ni]); }
                    if constexpr (OBLK) {
                        size_t o = (size_t)(col >> 5) * ((size_t)NNP * 32) +
                                   (size_t)row * 32 + (col & 31);
                        unsigned short hi = f2bf(v);
                        OHs[o] = hi;
                        OLs[o] = f2bf(v - bf2f(hi));
                    } else {
                        C[(size_t)row * NCOLS + col] = v;
                    }
                }
            }
        }
    }

    if constexpr (STATS) {
        __shared__ float s_sum[128], s_sq[128];
        if (tid < 128) { s_sum[tid] = 0.f; s_sq[tid] = 0.f; }
        __syncthreads();
#pragma unroll
        for (int ni = 0; ni < 4; ++ni) {
            float a = psum[ni], q = psq[ni];
            a += __shfl_xor(a, 16); a += __shfl_xor(a, 32);
            q += __shfl_xor(q, 16); q += __shfl_xor(q, 32);
            if ((lane >> 4) == 0) {
                int cl = wn * 64 + ni * 16 + lane;   // lane < 16 here
                atomicAdd(&s_sum[cl], a);
                atomicAdd(&s_sq[cl], q);
            }
        }
        __syncthreads();
        if (tid < 128) {
            atomicAdd(&statsOut[col0 + tid], s_sum[tid]);
            atomicAdd(&statsOut[256 + col0 + tid], s_sq[tid]);
        }
    }
}

extern "C" void kernel_launch(void* const* d_in, const int* in_sizes, int n_in,
                              void* d_out, int out_size, void* d_ws, size_t ws_size,
                              hipStream_t stream) {
    const float* feat  = (const float*)d_in[0];
    const int*   src   = (const int*)d_in[1];
    const int*   dst   = (const int*)d_in[2];
    const float* W0    = (const float*)d_in[3];
    const float* W1    = (const float*)d_in[4];
    const float* Wp1   = (const float*)d_in[5];
    const float* bp1   = (const float*)d_in[6];
    const float* gamma = (const float*)d_in[7];
    const float* beta  = (const float*)d_in[8];
    const float* Wp2   = (const float*)d_in[9];
    const float* bp2   = (const float*)d_in[10];
    float* out = (float*)d_out;

    char* wsb = (char*)d_ws;
    float* dinv   = (float*)(wsb + 4ull * 0);
    int*   cnt    = (int*)  (wsb + 4ull * 50048);
    int*   rowoff = (int*)  (wsb + 4ull * 100096);
    int*   cursor = (int*)  (wsb + 4ull * 150144);
    int*   bsum   = (int*)  (wsb + 4ull * 200192);
    int*   boff   = (int*)  (wsb + 4ull * 200448);
    int*   eidx   = (int*)  (wsb + 4ull * 200704);
    float* stats  = (float*)(wsb + 4ull * 1000704);
    float* bnscl  = (float*)(wsb + 4ull * 1001216);
    float* bnshf  = (float*)(wsb + 4ull * 1001472);
    float* W1p    = (float*)(wsb + 4ull * 1001728);          // [128][256] fp32
    unsigned short* W0tH  = (unsigned short*)(wsb + 4ull * 1034496);
    unsigned short* W0tL  = W0tH + 65536;
    unsigned short* W1ptH = W0tL + 65536;
    unsigned short* W1ptL = W1ptH + 32768;
    unsigned short* Wp2tH = W1ptL + 32768;
    unsigned short* Wp2tL = Wp2tH + 32768;                   // ends word 1165568
    // blocked H buffers: [4][NNP][32] u16 each (3203072 words apiece)
    unsigned short* H0H = (unsigned short*)(wsb + 4ull * 1165568);
    unsigned short* H0L = (unsigned short*)(wsb + 4ull * 4368640);
    unsigned short* h1H = (unsigned short*)(wsb + 4ull * 7571712);
    unsigned short* h1L = (unsigned short*)(wsb + 4ull * 10774784);
    unsigned short* h2H = H0H;   // reuse after H0 consumed
    unsigned short* h2L = H0L;
    float* Z = (float*)(wsb + 4ull * 13977856);              // [NN][256] fp32

    const int GX = NNP / 128;  // 391

    // ---- CSR build ----
    hipMemsetAsync(cnt, 0, NN * sizeof(int), stream);
    hipMemsetAsync(cursor, 0, NN * sizeof(int), stream);
    k_count<<<(NE + 255) / 256, 256, 0, stream>>>(dst, cnt);
    k_dinv<<<(NN + 255) / 256, 256, 0, stream>>>(cnt, dinv);
    k_bsum<<<NB, 256, 0, stream>>>(cnt, bsum);
    k_scan_bsum<<<1, 256, 0, stream>>>(bsum, boff);
    k_scan_block<<<NB, 256, 0, stream>>>(cnt, boff, rowoff);
    k_fill<<<(NE + 255) / 256, 256, 0, stream>>>(src, dst, rowoff, cursor, eidx);

    // ---- weight prep ----
    k_wsplit<<<(512 * 128 + 255) / 256, 256, 0, stream>>>(W0, W0tH, W0tL, 512, 128);
    k_mm128<<<128, 256, 0, stream>>>(W1, Wp1, W1p);                    // W1p = W1 @ Wp1
    k_wsplit<<<(128 * 256 + 255) / 256, 256, 0, stream>>>(W1p, W1ptH, W1ptL, 128, 256);
    k_wsplit<<<(256 * 128 + 255) / 256, 256, 0, stream>>>(Wp2, Wp2tH, Wp2tL, 256, 128);

    // H0 = feat @ W0  (A fp32 reg-staged, B split 2-pass, blocked hi/lo output)
    k_mfma<512, 128, false, false, 1, false, true, false><<<dim3(GX, 1), 512, 0, stream>>>(
        nullptr, nullptr, feat, W0tH, W0tL, nullptr, nullptr, nullptr,
        nullptr, H0H, H0L, nullptr);

    // h1 = conv(H0); h2 = conv(h1)   [conv commutes with right-mult by W]
    k_gather_blk<<<dim3(NNP / 4, 4), 256, 0, stream>>>(H0H, H0L, dinv, rowoff, cnt, eidx, h1H, h1L);
    k_gather_blk<<<dim3(NNP / 4, 4), 256, 0, stream>>>(h1H, h1L, dinv, rowoff, cnt, eidx, h2H, h2L);

    // Z = h2 @ (W1@Wp1) + bp1  [NN,256], fused BN column stats
    hipMemsetAsync(stats, 0, 512 * sizeof(float), stream);
    k_mfma<128, 256, true, true, 0, true, false, true><<<dim3(GX, 2), 512, 0, stream>>>(
        h2H, h2L, nullptr, W1ptH, W1ptL, bp1, nullptr, nullptr,
        Z, nullptr, nullptr, stats);

    k_bnprep<<<1, 256, 0, stream>>>(stats, gamma, beta, bnscl, bnshf);

    // out = relu(BN(Z)) @ Wp2 + bp2  (BN fused into A staging)
    k_mfma<256, 128, true, false, 2, false, false, false><<<dim3(GX, 1), 512, 0, stream>>>(
        nullptr, nullptr, Z, Wp2tH, Wp2tL, bp2, bnscl, bnshf,
        out, nullptr, nullptr, nullptr);
}

// Round 6
// 279.035 us; speedup vs baseline: 1.4977x; 1.4977x over previous
//
#include <hip/hip_runtime.h>
#include <math.h>

constexpr int NN  = 50000;
constexpr int NE  = 800000;
constexpr int NNP = 50048;             // padded rows = 391 * 128
constexpr int NB  = (NN + 255) / 256;  // scan blocks

typedef __bf16 bf16x8 __attribute__((ext_vector_type(8)));
typedef float  f32x4  __attribute__((ext_vector_type(4)));
typedef __attribute__((address_space(1))) unsigned int as1_uint;
typedef __attribute__((address_space(3))) unsigned int as3_uint;

__device__ __forceinline__ unsigned short f2bf(float x) {  // RNE fp32->bf16 bits
    unsigned int u = __float_as_uint(x);
    return (unsigned short)((u + 0x7FFFu + ((u >> 16) & 1u)) >> 16);
}
__device__ __forceinline__ float bf2f(unsigned short h) {
    return __uint_as_float(((unsigned int)h) << 16);
}

__device__ __forceinline__ void gload16(const unsigned short* g, unsigned short* l) {
    __builtin_amdgcn_global_load_lds((const as1_uint*)(unsigned long long)g,
                                     (as3_uint*)(unsigned long long)l, 16, 0, 0);
}

// ---------------- CSR build ----------------
__global__ void k_count(const int* __restrict__ dst, int* __restrict__ cnt) {
    int i = blockIdx.x * blockDim.x + threadIdx.x;
    if (i < NE) atomicAdd(&cnt[dst[i]], 1);
}

__global__ void k_dinv(const int* __restrict__ cnt, float* __restrict__ dinv) {
    int i = blockIdx.x * blockDim.x + threadIdx.x;
    if (i < NN) dinv[i] = rsqrtf(fmaxf((float)cnt[i], 1.0f));
}

__global__ void k_bsum(const int* __restrict__ cnt, int* __restrict__ bsum) {
    int i = blockIdx.x * 256 + threadIdx.x;
    int v = (i < NN) ? cnt[i] : 0;
#pragma unroll
    for (int off = 32; off; off >>= 1) v += __shfl_down(v, off, 64);
    __shared__ int tmp[4];
    if ((threadIdx.x & 63) == 0) tmp[threadIdx.x >> 6] = v;
    __syncthreads();
    if (threadIdx.x == 0) bsum[blockIdx.x] = tmp[0] + tmp[1] + tmp[2] + tmp[3];
}

__global__ void k_scan_bsum(const int* __restrict__ bsum, int* __restrict__ boff) {
    __shared__ int s[256];
    int t = threadIdx.x;
    int v = (t < NB) ? bsum[t] : 0;
    s[t] = v;
    __syncthreads();
    for (int off = 1; off < 256; off <<= 1) {
        int u = (t >= off) ? s[t - off] : 0;
        __syncthreads();
        s[t] += u;
        __syncthreads();
    }
    if (t < NB) boff[t] = s[t] - v;
}

__global__ void k_scan_block(const int* __restrict__ cnt, const int* __restrict__ boff,
                             int* __restrict__ rowoff) {
    __shared__ int s[256];
    int t = threadIdx.x;
    int i = blockIdx.x * 256 + t;
    int v = (i < NN) ? cnt[i] : 0;
    s[t] = v;
    __syncthreads();
    for (int off = 1; off < 256; off <<= 1) {
        int u = (t >= off) ? s[t - off] : 0;
        __syncthreads();
        s[t] += u;
        __syncthreads();
    }
    if (i < NN) rowoff[i] = boff[blockIdx.x] + s[t] - v;
}

__global__ void k_fill(const int* __restrict__ src, const int* __restrict__ dst,
                       const int* __restrict__ rowoff, int* __restrict__ cursor,
                       int* __restrict__ eidx) {
    int e = blockIdx.x * blockDim.x + threadIdx.x;
    if (e < NE) {
        int d = dst[e];
        int p = atomicAdd(&cursor[d], 1);
        eidx[rowoff[d] + p] = src[e];
    }
}

// ---------------- flat low_conv gather, MLP-optimized ----------------
// wave = 1 node; lanes = (2 edges) x (32 cols x ushort4). unroll x2 -> 4 edge
// chains (12 loads) in flight. shfl_down(32) combines the halves.
__global__ __launch_bounds__(256) void k_gather4(
    const unsigned short* __restrict__ HH, const unsigned short* __restrict__ HL,
    const float* __restrict__ dinv, const int* __restrict__ rowoff,
    const int* __restrict__ cnt, const int* __restrict__ eidx,
    unsigned short* __restrict__ OH, unsigned short* __restrict__ OL)
{
    int node = blockIdx.x * 4 + (threadIdx.x >> 6);
    int lane = threadIdx.x & 63;
    int c = (lane & 31) * 4;
    int e = lane >> 5;
    if (node >= NNP) return;
    size_t rb = (size_t)node * 128;
    if (node >= NN) {  // zero pad rows
        if (e == 0) {
            *reinterpret_cast<ushort4*>(&OH[rb + c]) = make_ushort4(0, 0, 0, 0);
            *reinterpret_cast<ushort4*>(&OL[rb + c]) = make_ushort4(0, 0, 0, 0);
        }
        return;
    }
    int beg = rowoff[node], n = cnt[node];
    float a0 = 0.f, a1 = 0.f, a2 = 0.f, a3 = 0.f;
    int j = 0;
    for (; j + 4 <= n; j += 4) {  // this half-wave: edges j+e, j+e+2
        int sA = eidx[beg + j + e];
        int sB = eidx[beg + j + e + 2];
        float dA = dinv[sA], dB = dinv[sB];
        ushort4 vA = *reinterpret_cast<const ushort4*>(&HH[(size_t)sA * 128 + c]);
        ushort4 vB = *reinterpret_cast<const ushort4*>(&HH[(size_t)sB * 128 + c]);
        a0 = fmaf(bf2f(vA.x), dA, a0);
        a1 = fmaf(bf2f(vA.y), dA, a1);
        a2 = fmaf(bf2f(vA.z), dA, a2);
        a3 = fmaf(bf2f(vA.w), dA, a3);
        a0 = fmaf(bf2f(vB.x), dB, a0);
        a1 = fmaf(bf2f(vB.y), dB, a1);
        a2 = fmaf(bf2f(vB.z), dB, a2);
        a3 = fmaf(bf2f(vB.w), dB, a3);
    }
    while (j + e < n) {  // tail: <=2 iters per half
        int s = eidx[beg + j + e];
        float d = dinv[s];
        ushort4 v = *reinterpret_cast<const ushort4*>(&HH[(size_t)s * 128 + c]);
        a0 = fmaf(bf2f(v.x), d, a0);
        a1 = fmaf(bf2f(v.y), d, a1);
        a2 = fmaf(bf2f(v.z), d, a2);
        a3 = fmaf(bf2f(v.w), d, a3);
        j += 2;
    }
    a0 += __shfl_down(a0, 32);
    a1 += __shfl_down(a1, 32);
    a2 += __shfl_down(a2, 32);
    a3 += __shfl_down(a3, 32);
    if (e == 0) {
        float d = dinv[node];
        ushort4 sh = *reinterpret_cast<const ushort4*>(&HH[rb + c]);
        ushort4 sl = *reinterpret_cast<const ushort4*>(&HL[rb + c]);
        float h0 = fmaf(a0, d, bf2f(sh.x) + bf2f(sl.x));
        float h1 = fmaf(a1, d, bf2f(sh.y) + bf2f(sl.y));
        float h2 = fmaf(a2, d, bf2f(sh.z) + bf2f(sl.z));
        float h3 = fmaf(a3, d, bf2f(sh.w) + bf2f(sl.w));
        ushort4 hv, lv;
        hv.x = f2bf(h0); lv.x = f2bf(h0 - bf2f(hv.x));
        hv.y = f2bf(h1); lv.y = f2bf(h1 - bf2f(hv.y));
        hv.z = f2bf(h2); lv.z = f2bf(h2 - bf2f(hv.z));
        hv.w = f2bf(h3); lv.w = f2bf(h3 - bf2f(hv.w));
        *reinterpret_cast<ushort4*>(&OH[rb + c]) = hv;
        *reinterpret_cast<ushort4*>(&OL[rb + c]) = lv;
    }
}

// ---------------- small fp32 GEMM on weights: W1p[128][256] = W1 @ Wp1 ----------------
__global__ void k_mm128(const float* __restrict__ W1, const float* __restrict__ Wp1,
                        float* __restrict__ W1p) {
    int i = blockIdx.x;    // 128
    int j = threadIdx.x;   // 256
    float s = 0.f;
    for (int k = 0; k < 128; ++k) s = fmaf(W1[i * 128 + k], Wp1[k * 256 + j], s);
    W1p[i * 256 + j] = s;
}

// ---------------- weight transpose + hi/lo split: W[K][N] -> Wt[N][K] ----------------
__global__ void k_wsplit(const float* __restrict__ W, unsigned short* __restrict__ th,
                         unsigned short* __restrict__ tl, int K, int N) {
    int idx = blockIdx.x * blockDim.x + threadIdx.x;
    if (idx < K * N) {
        int k = idx / N, n = idx - k * N;
        float a = W[idx];
        unsigned short hi = f2bf(a);
        float lo = a - bf2f(hi);
        th[(size_t)n * K + k] = hi;
        tl[(size_t)n * K + k] = f2bf(lo);
    }
}

// ---------------- BN prep: stats -> scale/shift ----------------
__global__ void k_bnprep(const float* __restrict__ stats, const float* __restrict__ gamma,
                         const float* __restrict__ beta, float* __restrict__ scale,
                         float* __restrict__ shift) {
    int c = threadIdx.x;
    float mu  = stats[c] * (1.0f / NN);
    float var = stats[256 + c] * (1.0f / NN) - mu * mu;
    float s = gamma[c] * rsqrtf(var + 1e-5f);
    scale[c] = s;
    shift[c] = beta[c] - mu * s;
}

// ---------------- split-precision MFMA GEMM (flat layouts) ----------------
// AMODE: 0 = bf16 hi(/lo) via global_load_lds; 1 = fp32 reg-staged -> bf16;
//        2 = fp32 reg-staged with BN(scale/shift)+ReLU -> bf16.
// OSPLIT: emit flat bf16 hi/lo outputs. STATS: per-column sum/sumsq of C.
template <int K, int NCOLS, bool BIAS, bool ALO, int AMODE, bool OSPLIT, bool STATS>
__global__ __launch_bounds__(512) void k_mfma(
    const unsigned short* __restrict__ AH, const unsigned short* __restrict__ AL,
    const float* __restrict__ Af,
    const unsigned short* __restrict__ BH, const unsigned short* __restrict__ BL,
    const float* __restrict__ bias,
    const float* __restrict__ bnscl, const float* __restrict__ bnshf,
    float* __restrict__ C, unsigned short* __restrict__ OHs, unsigned short* __restrict__ OLs,
    float* __restrict__ statsOut)
{
    __shared__ __align__(16) unsigned short lds[4 * 4096];
    unsigned short* ldsAH = lds;
    unsigned short* ldsAL = lds + 4096;
    unsigned short* ldsBH = lds + 8192;
    unsigned short* ldsBL = lds + 12288;

    const int tid  = threadIdx.x;
    const int lane = tid & 63;
    const int wid  = tid >> 6;
    const int wm   = wid >> 1;
    const int wn   = wid & 1;
    const int row0 = blockIdx.x * 128;
    const int col0 = blockIdx.y * 128;

    const int srow  = tid >> 2;
    const int skg   = tid & 3;
    const int skswz = skg ^ ((srow >> 1) & 3);  // inverse swizzle on SOURCE
    const size_t aSrc = (size_t)(row0 + srow) * K + skswz * 8;
    const size_t bSrc = (size_t)(col0 + srow) * K + skswz * 8;

    const int frow = lane & 15;
    const int fkg  = lane >> 4;

    f32x4 acc[2][4] = {};

    for (int k0 = 0; k0 < K; k0 += 32) {
        if constexpr (AMODE == 1) {
            float4 f0, f1;
            if (row0 + srow < NN) {
                const float* ap = Af + aSrc + k0;
                f0 = *reinterpret_cast<const float4*>(ap);
                f1 = *reinterpret_cast<const float4*>(ap + 4);
            } else {
                f0 = make_float4(0.f, 0.f, 0.f, 0.f);
                f1 = f0;
            }
            uint4 w;
            w.x = (unsigned)f2bf(f0.x) | ((unsigned)f2bf(f0.y) << 16);
            w.y = (unsigned)f2bf(f0.z) | ((unsigned)f2bf(f0.w) << 16);
            w.z = (unsigned)f2bf(f1.x) | ((unsigned)f2bf(f1.y) << 16);
            w.w = (unsigned)f2bf(f1.z) | ((unsigned)f2bf(f1.w) << 16);
            *reinterpret_cast<uint4*>(&ldsAH[tid * 8]) = w;
        } else if constexpr (AMODE == 2) {
            float4 f0, f1;
            if (row0 + srow < NN) {
                const float* ap = Af + aSrc + k0;
                f0 = *reinterpret_cast<const float4*>(ap);
                f1 = *reinterpret_cast<const float4*>(ap + 4);
            } else {
                f0 = make_float4(0.f, 0.f, 0.f, 0.f);
                f1 = f0;
            }
            int kc = k0 + skswz * 8;
            float4 s0 = *reinterpret_cast<const float4*>(&bnscl[kc]);
            float4 s1 = *reinterpret_cast<const float4*>(&bnscl[kc + 4]);
            float4 t0 = *reinterpret_cast<const float4*>(&bnshf[kc]);
            float4 t1 = *reinterpret_cast<const float4*>(&bnshf[kc + 4]);
            float v0 = fmaxf(fmaf(f0.x, s0.x, t0.x), 0.f);
            float v1 = fmaxf(fmaf(f0.y, s0.y, t0.y), 0.f);
            float v2 = fmaxf(fmaf(f0.z, s0.z, t0.z), 0.f);
            float v3 = fmaxf(fmaf(f0.w, s0.w, t0.w), 0.f);
            float v4 = fmaxf(fmaf(f1.x, s1.x, t1.x), 0.f);
            float v5 = fmaxf(fmaf(f1.y, s1.y, t1.y), 0.f);
            float v6 = fmaxf(fmaf(f1.z, s1.z, t1.z), 0.f);
            float v7 = fmaxf(fmaf(f1.w, s1.w, t1.w), 0.f);
            uint4 w;
            w.x = (unsigned)f2bf(v0) | ((unsigned)f2bf(v1) << 16);
            w.y = (unsigned)f2bf(v2) | ((unsigned)f2bf(v3) << 16);
            w.z = (unsigned)f2bf(v4) | ((unsigned)f2bf(v5) << 16);
            w.w = (unsigned)f2bf(v6) | ((unsigned)f2bf(v7) << 16);
            *reinterpret_cast<uint4*>(&ldsAH[tid * 8]) = w;
        } else {
            gload16(AH + aSrc + k0, ldsAH + tid * 8);
            if constexpr (ALO) gload16(AL + aSrc + k0, ldsAL + tid * 8);
        }
        gload16(BH + bSrc + k0, ldsBH + tid * 8);
        gload16(BL + bSrc + k0, ldsBL + tid * 8);
        __syncthreads();

        bf16x8 a_h[2], a_l[2], b_h[4], b_l[4];
#pragma unroll
        for (int mi = 0; mi < 2; ++mi) {
            int ar  = wm * 32 + mi * 16 + frow;
            int idx = ar * 32 + ((fkg ^ ((ar >> 1) & 3)) * 8);
            a_h[mi] = *reinterpret_cast<const bf16x8*>(&ldsAH[idx]);
            if constexpr (ALO) a_l[mi] = *reinterpret_cast<const bf16x8*>(&ldsAL[idx]);
        }
#pragma unroll
        for (int ni = 0; ni < 4; ++ni) {
            int bc  = wn * 64 + ni * 16 + frow;
            int idx = bc * 32 + ((fkg ^ ((bc >> 1) & 3)) * 8);
            b_h[ni] = *reinterpret_cast<const bf16x8*>(&ldsBH[idx]);
            b_l[ni] = *reinterpret_cast<const bf16x8*>(&ldsBL[idx]);
        }
#pragma unroll
        for (int mi = 0; mi < 2; ++mi)
#pragma unroll
            for (int ni = 0; ni < 4; ++ni) {
                acc[mi][ni] = __builtin_amdgcn_mfma_f32_16x16x32_bf16(a_h[mi], b_h[ni], acc[mi][ni], 0, 0, 0);
                acc[mi][ni] = __builtin_amdgcn_mfma_f32_16x16x32_bf16(a_h[mi], b_l[ni], acc[mi][ni], 0, 0, 0);
                if constexpr (ALO)
                    acc[mi][ni] = __builtin_amdgcn_mfma_f32_16x16x32_bf16(a_l[mi], b_h[ni], acc[mi][ni], 0, 0, 0);
            }
        __syncthreads();
    }

    float psum[4] = {0.f, 0.f, 0.f, 0.f}, psq[4] = {0.f, 0.f, 0.f, 0.f};
#pragma unroll
    for (int mi = 0; mi < 2; ++mi) {
        int rbase = row0 + wm * 32 + mi * 16 + (lane >> 4) * 4;
#pragma unroll
        for (int ni = 0; ni < 4; ++ni) {
            int col = col0 + wn * 64 + ni * 16 + (lane & 15);
            float b = BIAS ? bias[col] : 0.f;
#pragma unroll
            for (int r = 0; r < 4; ++r) {
                int row = rbase + r;
                if (row < NN) {
                    float v = acc[mi][ni][r] + b;
                    if constexpr (STATS) { psum[ni] += v; psq[ni] = fmaf(v, v, psq[ni]); }
                    if constexpr (OSPLIT) {
                        unsigned short hi = f2bf(v);
                        OHs[(size_t)row * NCOLS + col] = hi;
                        OLs[(size_t)row * NCOLS + col] = f2bf(v - bf2f(hi));
                    } else {
                        C[(size_t)row * NCOLS + col] = v;
                    }
                }
            }
        }
    }

    if constexpr (STATS) {
        __shared__ float s_sum[128], s_sq[128];
        if (tid < 128) { s_sum[tid] = 0.f; s_sq[tid] = 0.f; }
        __syncthreads();
#pragma unroll
        for (int ni = 0; ni < 4; ++ni) {
            float a = psum[ni], q = psq[ni];
            a += __shfl_xor(a, 16); a += __shfl_xor(a, 32);
            q += __shfl_xor(q, 16); q += __shfl_xor(q, 32);
            if ((lane >> 4) == 0) {
                int cl = wn * 64 + ni * 16 + lane;   // lane < 16 here
                atomicAdd(&s_sum[cl], a);
                atomicAdd(&s_sq[cl], q);
            }
        }
        __syncthreads();
        if (tid < 128) {
            atomicAdd(&statsOut[col0 + tid], s_sum[tid]);
            atomicAdd(&statsOut[256 + col0 + tid], s_sq[tid]);
        }
    }
}

extern "C" void kernel_launch(void* const* d_in, const int* in_sizes, int n_in,
                              void* d_out, int out_size, void* d_ws, size_t ws_size,
                              hipStream_t stream) {
    const float* feat  = (const float*)d_in[0];
    const int*   src   = (const int*)d_in[1];
    const int*   dst   = (const int*)d_in[2];
    const float* W0    = (const float*)d_in[3];
    const float* W1    = (const float*)d_in[4];
    const float* Wp1   = (const float*)d_in[5];
    const float* bp1   = (const float*)d_in[6];
    const float* gamma = (const float*)d_in[7];
    const float* beta  = (const float*)d_in[8];
    const float* Wp2   = (const float*)d_in[9];
    const float* bp2   = (const float*)d_in[10];
    float* out = (float*)d_out;

    char* wsb = (char*)d_ws;
    float* dinv   = (float*)(wsb + 4ull * 0);
    int*   cnt    = (int*)  (wsb + 4ull * 50048);
    int*   rowoff = (int*)  (wsb + 4ull * 100096);
    int*   cursor = (int*)  (wsb + 4ull * 150144);
    int*   bsum   = (int*)  (wsb + 4ull * 200192);
    int*   boff   = (int*)  (wsb + 4ull * 200448);
    int*   eidx   = (int*)  (wsb + 4ull * 200704);
    float* stats  = (float*)(wsb + 4ull * 1000704);
    float* bnscl  = (float*)(wsb + 4ull * 1001216);
    float* bnshf  = (float*)(wsb + 4ull * 1001472);
    float* W1p    = (float*)(wsb + 4ull * 1001728);          // [128][256] fp32
    unsigned short* W0tH  = (unsigned short*)(wsb + 4ull * 1034496);
    unsigned short* W0tL  = W0tH + 65536;
    unsigned short* W1ptH = W0tL + 65536;
    unsigned short* W1ptL = W1ptH + 32768;
    unsigned short* Wp2tH = W1ptL + 32768;
    unsigned short* Wp2tL = Wp2tH + 32768;                   // ends word 1165568
    // flat H buffers: [NNP][128] u16 each (3203072 words apiece)
    unsigned short* H0H = (unsigned short*)(wsb + 4ull * 1165568);
    unsigned short* H0L = (unsigned short*)(wsb + 4ull * 4368640);
    unsigned short* h1H = (unsigned short*)(wsb + 4ull * 7571712);
    unsigned short* h1L = (unsigned short*)(wsb + 4ull * 10774784);
    unsigned short* h2H = H0H;   // reuse after H0 consumed
    unsigned short* h2L = H0L;
    float* Z = (float*)(wsb + 4ull * 13977856);              // [NN][256] fp32

    const int GX = NNP / 128;  // 391

    // ---- CSR build ----
    hipMemsetAsync(cnt, 0, NN * sizeof(int), stream);
    hipMemsetAsync(cursor, 0, NN * sizeof(int), stream);
    k_count<<<(NE + 255) / 256, 256, 0, stream>>>(dst, cnt);
    k_dinv<<<(NN + 255) / 256, 256, 0, stream>>>(cnt, dinv);
    k_bsum<<<NB, 256, 0, stream>>>(cnt, bsum);
    k_scan_bsum<<<1, 256, 0, stream>>>(bsum, boff);
    k_scan_block<<<NB, 256, 0, stream>>>(cnt, boff, rowoff);
    k_fill<<<(NE + 255) / 256, 256, 0, stream>>>(src, dst, rowoff, cursor, eidx);

    // ---- weight prep ----
    k_wsplit<<<(512 * 128 + 255) / 256, 256, 0, stream>>>(W0, W0tH, W0tL, 512, 128);
    k_mm128<<<128, 256, 0, stream>>>(W1, Wp1, W1p);                    // W1p = W1 @ Wp1
    k_wsplit<<<(128 * 256 + 255) / 256, 256, 0, stream>>>(W1p, W1ptH, W1ptL, 128, 256);
    k_wsplit<<<(256 * 128 + 255) / 256, 256, 0, stream>>>(Wp2, Wp2tH, Wp2tL, 256, 128);

    // H0 = feat @ W0  (A fp32 reg-staged, B split 2-pass, flat hi/lo output)
    k_mfma<512, 128, false, false, 1, true, false><<<dim3(GX, 1), 512, 0, stream>>>(
        nullptr, nullptr, feat, W0tH, W0tL, nullptr, nullptr, nullptr,
        nullptr, H0H, H0L, nullptr);

    // h1 = conv(H0); h2 = conv(h1)   [conv commutes with right-mult by W]
    k_gather4<<<NNP / 4, 256, 0, stream>>>(H0H, H0L, dinv, rowoff, cnt, eidx, h1H, h1L);
    k_gather4<<<NNP / 4, 256, 0, stream>>>(h1H, h1L, dinv, rowoff, cnt, eidx, h2H, h2L);

    // Z = h2 @ (W1@Wp1) + bp1  [NN,256], fused BN column stats
    hipMemsetAsync(stats, 0, 512 * sizeof(float), stream);
    k_mfma<128, 256, true, true, 0, false, true><<<dim3(GX, 2), 512, 0, stream>>>(
        h2H, h2L, nullptr, W1ptH, W1ptL, bp1, nullptr, nullptr,
        Z, nullptr, nullptr, stats);

    k_bnprep<<<1, 256, 0, stream>>>(stats, gamma, beta, bnscl, bnshf);

    // out = relu(BN(Z)) @ Wp2 + bp2  (BN fused into A staging)
    k_mfma<256, 128, true, false, 2, false, false><<<dim3(GX, 1), 512, 0, stream>>>(
        nullptr, nullptr, Z, Wp2tH, Wp2tL, bp2, bnscl, bnshf,
        out, nullptr, nullptr, nullptr);
}

// Round 7
// 270.286 us; speedup vs baseline: 1.5462x; 1.0324x over previous
//
#include <hip/hip_runtime.h>
#include <math.h>

constexpr int NN  = 50000;
constexpr int NE  = 800000;
constexpr int NNP = 50048;             // padded rows = 391 * 128
constexpr int NB  = (NN + 255) / 256;  // scan blocks

typedef __bf16 bf16x8 __attribute__((ext_vector_type(8)));
typedef float  f32x4  __attribute__((ext_vector_type(4)));
typedef __attribute__((address_space(1))) unsigned int as1_uint;
typedef __attribute__((address_space(3))) unsigned int as3_uint;

__device__ __forceinline__ unsigned short f2bf(float x) {  // RNE fp32->bf16 bits
    unsigned int u = __float_as_uint(x);
    return (unsigned short)((u + 0x7FFFu + ((u >> 16) & 1u)) >> 16);
}
__device__ __forceinline__ float bf2f(unsigned short h) {
    return __uint_as_float(((unsigned int)h) << 16);
}

__device__ __forceinline__ void gload16(const unsigned short* g, unsigned short* l) {
    __builtin_amdgcn_global_load_lds((const as1_uint*)(unsigned long long)g,
                                     (as3_uint*)(unsigned long long)l, 16, 0, 0);
}

// ---------------- CSR build ----------------
__global__ void k_count(const int* __restrict__ dst, int* __restrict__ cnt) {
    int i = blockIdx.x * blockDim.x + threadIdx.x;
    if (i < NE) atomicAdd(&cnt[dst[i]], 1);
}

__global__ void k_bsum(const int* __restrict__ cnt, int* __restrict__ bsum) {
    int i = blockIdx.x * 256 + threadIdx.x;
    int v = (i < NN) ? cnt[i] : 0;
#pragma unroll
    for (int off = 32; off; off >>= 1) v += __shfl_down(v, off, 64);
    __shared__ int tmp[4];
    if ((threadIdx.x & 63) == 0) tmp[threadIdx.x >> 6] = v;
    __syncthreads();
    if (threadIdx.x == 0) bsum[blockIdx.x] = tmp[0] + tmp[1] + tmp[2] + tmp[3];
}

__global__ void k_scan_bsum(const int* __restrict__ bsum, int* __restrict__ boff) {
    __shared__ int s[256];
    int t = threadIdx.x;
    int v = (t < NB) ? bsum[t] : 0;
    s[t] = v;
    __syncthreads();
    for (int off = 1; off < 256; off <<= 1) {
        int u = (t >= off) ? s[t - off] : 0;
        __syncthreads();
        s[t] += u;
        __syncthreads();
    }
    if (t < NB) boff[t] = s[t] - v;
}

// also emits dinv (folded k_dinv)
__global__ void k_scan_block(const int* __restrict__ cnt, const int* __restrict__ boff,
                             int* __restrict__ rowoff, float* __restrict__ dinv) {
    __shared__ int s[256];
    int t = threadIdx.x;
    int i = blockIdx.x * 256 + t;
    int v = (i < NN) ? cnt[i] : 0;
    s[t] = v;
    __syncthreads();
    for (int off = 1; off < 256; off <<= 1) {
        int u = (t >= off) ? s[t - off] : 0;
        __syncthreads();
        s[t] += u;
        __syncthreads();
    }
    if (i < NN) {
        rowoff[i] = boff[blockIdx.x] + s[t] - v;
        dinv[i] = rsqrtf(fmaxf((float)v, 1.0f));
    }
}

__global__ void k_fill(const int* __restrict__ src, const int* __restrict__ dst,
                       const int* __restrict__ rowoff, int* __restrict__ cursor,
                       int* __restrict__ eidx) {
    int e = blockIdx.x * blockDim.x + threadIdx.x;
    if (e < NE) {
        int d = dst[e];
        int p = atomicAdd(&cursor[d], 1);
        eidx[rowoff[d] + p] = src[e];
    }
}

// ---------------- flat low_conv gather, deep-MLP ----------------
// wave = 1 node; lanes = (2 edge-chains) x (32 cols x ushort4). unroll x4 ->
// 8 independent row-loads in flight per wave. shfl_down(32) combines halves.
__global__ __launch_bounds__(256) void k_gather4(
    const unsigned short* __restrict__ HH, const unsigned short* __restrict__ HL,
    const float* __restrict__ dinv, const int* __restrict__ rowoff,
    const int* __restrict__ cnt, const int* __restrict__ eidx,
    unsigned short* __restrict__ OH, unsigned short* __restrict__ OL)
{
    int node = blockIdx.x * 4 + (threadIdx.x >> 6);
    int lane = threadIdx.x & 63;
    int c = (lane & 31) * 4;
    int e = lane >> 5;
    if (node >= NNP) return;
    size_t rb = (size_t)node * 128;
    if (node >= NN) {  // zero pad rows
        if (e == 0) {
            *reinterpret_cast<ushort4*>(&OH[rb + c]) = make_ushort4(0, 0, 0, 0);
            *reinterpret_cast<ushort4*>(&OL[rb + c]) = make_ushort4(0, 0, 0, 0);
        }
        return;
    }
    int beg = rowoff[node], n = cnt[node];
    float a0 = 0.f, a1 = 0.f, a2 = 0.f, a3 = 0.f;
    int j = 0;
    for (; j + 8 <= n; j += 8) {  // this half-wave: edges j+e, j+e+2, j+e+4, j+e+6
        int s0 = eidx[beg + j + e];
        int s1 = eidx[beg + j + e + 2];
        int s2 = eidx[beg + j + e + 4];
        int s3 = eidx[beg + j + e + 6];
        float d0 = dinv[s0], d1 = dinv[s1], d2 = dinv[s2], d3 = dinv[s3];
        ushort4 v0 = *reinterpret_cast<const ushort4*>(&HH[(size_t)s0 * 128 + c]);
        ushort4 v1 = *reinterpret_cast<const ushort4*>(&HH[(size_t)s1 * 128 + c]);
        ushort4 v2 = *reinterpret_cast<const ushort4*>(&HH[(size_t)s2 * 128 + c]);
        ushort4 v3 = *reinterpret_cast<const ushort4*>(&HH[(size_t)s3 * 128 + c]);
        a0 = fmaf(bf2f(v0.x), d0, a0); a1 = fmaf(bf2f(v0.y), d0, a1);
        a2 = fmaf(bf2f(v0.z), d0, a2); a3 = fmaf(bf2f(v0.w), d0, a3);
        a0 = fmaf(bf2f(v1.x), d1, a0); a1 = fmaf(bf2f(v1.y), d1, a1);
        a2 = fmaf(bf2f(v1.z), d1, a2); a3 = fmaf(bf2f(v1.w), d1, a3);
        a0 = fmaf(bf2f(v2.x), d2, a0); a1 = fmaf(bf2f(v2.y), d2, a1);
        a2 = fmaf(bf2f(v2.z), d2, a2); a3 = fmaf(bf2f(v2.w), d2, a3);
        a0 = fmaf(bf2f(v3.x), d3, a0); a1 = fmaf(bf2f(v3.y), d3, a1);
        a2 = fmaf(bf2f(v3.z), d3, a2); a3 = fmaf(bf2f(v3.w), d3, a3);
    }
    while (j + e < n) {  // tail, stride 2 per half
        int s = eidx[beg + j + e];
        float d = dinv[s];
        ushort4 v = *reinterpret_cast<const ushort4*>(&HH[(size_t)s * 128 + c]);
        a0 = fmaf(bf2f(v.x), d, a0); a1 = fmaf(bf2f(v.y), d, a1);
        a2 = fmaf(bf2f(v.z), d, a2); a3 = fmaf(bf2f(v.w), d, a3);
        j += 2;
    }
    a0 += __shfl_down(a0, 32);
    a1 += __shfl_down(a1, 32);
    a2 += __shfl_down(a2, 32);
    a3 += __shfl_down(a3, 32);
    if (e == 0) {
        float d = dinv[node];
        ushort4 sh = *reinterpret_cast<const ushort4*>(&HH[rb + c]);
        ushort4 sl = *reinterpret_cast<const ushort4*>(&HL[rb + c]);
        float h0 = fmaf(a0, d, bf2f(sh.x) + bf2f(sl.x));
        float h1 = fmaf(a1, d, bf2f(sh.y) + bf2f(sl.y));
        float h2 = fmaf(a2, d, bf2f(sh.z) + bf2f(sl.z));
        float h3 = fmaf(a3, d, bf2f(sh.w) + bf2f(sl.w));
        ushort4 hv, lv;
        hv.x = f2bf(h0); lv.x = f2bf(h0 - bf2f(hv.x));
        hv.y = f2bf(h1); lv.y = f2bf(h1 - bf2f(hv.y));
        hv.z = f2bf(h2); lv.z = f2bf(h2 - bf2f(hv.z));
        hv.w = f2bf(h3); lv.w = f2bf(h3 - bf2f(hv.w));
        *reinterpret_cast<ushort4*>(&OH[rb + c]) = hv;
        *reinterpret_cast<ushort4*>(&OL[rb + c]) = lv;
    }
}

// ---------------- W1p = W1 @ Wp1 (fp32), also zeroes stats ----------------
__global__ void k_mm128(const float* __restrict__ W1, const float* __restrict__ Wp1,
                        float* __restrict__ W1p, float* __restrict__ stats) {
    int i = blockIdx.x;    // 128
    int j = threadIdx.x;   // 256
    if (i < 2) stats[i * 256 + j] = 0.f;   // fold stats memset
    float s = 0.f;
    for (int k = 0; k < 128; ++k) s = fmaf(W1[i * 128 + k], Wp1[k * 256 + j], s);
    W1p[i * 256 + j] = s;
}

// ---------------- all weight transposes + hi/lo splits in one launch ----------------
__global__ void k_wsplit_all(const float* __restrict__ W0, const float* __restrict__ W1p,
                             const float* __restrict__ Wp2,
                             unsigned short* __restrict__ W0tH, unsigned short* __restrict__ W0tL,
                             unsigned short* __restrict__ W1ptH, unsigned short* __restrict__ W1ptL,
                             unsigned short* __restrict__ Wp2tH, unsigned short* __restrict__ Wp2tL) {
    int idx = blockIdx.x * blockDim.x + threadIdx.x;
    const float* W; unsigned short *th, *tl; int K, N, local;
    if (idx < 65536)       { W = W0;  th = W0tH;  tl = W0tL;  K = 512; N = 128; local = idx; }
    else if (idx < 98304)  { W = W1p; th = W1ptH; tl = W1ptL; K = 128; N = 256; local = idx - 65536; }
    else if (idx < 131072) { W = Wp2; th = Wp2tH; tl = Wp2tL; K = 256; N = 128; local = idx - 98304; }
    else return;
    int k = local / N, n = local - k * N;
    float a = W[local];
    unsigned short hi = f2bf(a);
    th[(size_t)n * K + k] = hi;
    tl[(size_t)n * K + k] = f2bf(a - bf2f(hi));
}

// ---------------- split-precision MFMA GEMM (flat layouts) ----------------
// AMODE: 0 = bf16 hi(/lo) via global_load_lds; 1 = fp32 reg-staged -> bf16;
//        2 = fp32 reg-staged + BN(from raw stats/gamma/beta)+ReLU -> bf16 (fused bnprep).
// BLO: include B-lo pass. OSPLIT: flat bf16 hi/lo outputs. STATS: column sum/sumsq.
template <int K, int NCOLS, bool BIAS, bool ALO, bool BLO, int AMODE, bool OSPLIT, bool STATS>
__global__ __launch_bounds__(512) void k_mfma(
    const unsigned short* __restrict__ AH, const unsigned short* __restrict__ AL,
    const float* __restrict__ Af,
    const unsigned short* __restrict__ BH, const unsigned short* __restrict__ BL,
    const float* __restrict__ bias,
    const float* __restrict__ stats, const float* __restrict__ gamma,
    const float* __restrict__ beta,
    float* __restrict__ C, unsigned short* __restrict__ OHs, unsigned short* __restrict__ OLs,
    float* __restrict__ statsOut)
{
    __shared__ __align__(16) unsigned short lds[4 * 4096];
    unsigned short* ldsAH = lds;
    unsigned short* ldsAL = lds + 4096;
    unsigned short* ldsBH = lds + 8192;
    unsigned short* ldsBL = lds + 12288;

    const int tid  = threadIdx.x;
    const int lane = tid & 63;
    const int wid  = tid >> 6;
    const int wm   = wid >> 1;
    const int wn   = wid & 1;
    const int row0 = blockIdx.x * 128;
    const int col0 = blockIdx.y * 128;

    const int srow  = tid >> 2;
    const int skg   = tid & 3;
    const int skswz = skg ^ ((srow >> 1) & 3);  // inverse swizzle on SOURCE
    const size_t aSrc = (size_t)(row0 + srow) * K + skswz * 8;
    const size_t bSrc = (size_t)(col0 + srow) * K + skswz * 8;

    const int frow = lane & 15;
    const int fkg  = lane >> 4;

    f32x4 acc[2][4] = {};

    for (int k0 = 0; k0 < K; k0 += 32) {
        if constexpr (AMODE == 1 || AMODE == 2) {
            float4 f0, f1;
            if (row0 + srow < NN) {
                const float* ap = Af + aSrc + k0;
                f0 = *reinterpret_cast<const float4*>(ap);
                f1 = *reinterpret_cast<const float4*>(ap + 4);
            } else {
                f0 = make_float4(0.f, 0.f, 0.f, 0.f);
                f1 = f0;
            }
            float vv[8] = {f0.x, f0.y, f0.z, f0.w, f1.x, f1.y, f1.z, f1.w};
            if constexpr (AMODE == 2) {
                int kc = k0 + skswz * 8;
#pragma unroll
                for (int q = 0; q < 8; ++q) {
                    int kcol = kc + q;
                    float mu  = stats[kcol] * (1.0f / NN);
                    float var = stats[256 + kcol] * (1.0f / NN) - mu * mu;
                    float s = gamma[kcol] * rsqrtf(var + 1e-5f);
                    vv[q] = fmaxf(fmaf(vv[q] - mu, s, beta[kcol]), 0.f);
                }
            }
            uint4 w;
            w.x = (unsigned)f2bf(vv[0]) | ((unsigned)f2bf(vv[1]) << 16);
            w.y = (unsigned)f2bf(vv[2]) | ((unsigned)f2bf(vv[3]) << 16);
            w.z = (unsigned)f2bf(vv[4]) | ((unsigned)f2bf(vv[5]) << 16);
            w.w = (unsigned)f2bf(vv[6]) | ((unsigned)f2bf(vv[7]) << 16);
            *reinterpret_cast<uint4*>(&ldsAH[tid * 8]) = w;
        } else {
            gload16(AH + aSrc + k0, ldsAH + tid * 8);
            if constexpr (ALO) gload16(AL + aSrc + k0, ldsAL + tid * 8);
        }
        gload16(BH + bSrc + k0, ldsBH + tid * 8);
        if constexpr (BLO) gload16(BL + bSrc + k0, ldsBL + tid * 8);
        __syncthreads();

        bf16x8 a_h[2], a_l[2], b_h[4], b_l[4];
#pragma unroll
        for (int mi = 0; mi < 2; ++mi) {
            int ar  = wm * 32 + mi * 16 + frow;
            int idx = ar * 32 + ((fkg ^ ((ar >> 1) & 3)) * 8);
            a_h[mi] = *reinterpret_cast<const bf16x8*>(&ldsAH[idx]);
            if constexpr (ALO) a_l[mi] = *reinterpret_cast<const bf16x8*>(&ldsAL[idx]);
        }
#pragma unroll
        for (int ni = 0; ni < 4; ++ni) {
            int bc  = wn * 64 + ni * 16 + frow;
            int idx = bc * 32 + ((fkg ^ ((bc >> 1) & 3)) * 8);
            b_h[ni] = *reinterpret_cast<const bf16x8*>(&ldsBH[idx]);
            if constexpr (BLO) b_l[ni] = *reinterpret_cast<const bf16x8*>(&ldsBL[idx]);
        }
#pragma unroll
        for (int mi = 0; mi < 2; ++mi)
#pragma unroll
            for (int ni = 0; ni < 4; ++ni) {
                acc[mi][ni] = __builtin_amdgcn_mfma_f32_16x16x32_bf16(a_h[mi], b_h[ni], acc[mi][ni], 0, 0, 0);
                if constexpr (BLO)
                    acc[mi][ni] = __builtin_amdgcn_mfma_f32_16x16x32_bf16(a_h[mi], b_l[ni], acc[mi][ni], 0, 0, 0);
                if constexpr (ALO)
                    acc[mi][ni] = __builtin_amdgcn_mfma_f32_16x16x32_bf16(a_l[mi], b_h[ni], acc[mi][ni], 0, 0, 0);
            }
        __syncthreads();
    }

    float psum[4] = {0.f, 0.f, 0.f, 0.f}, psq[4] = {0.f, 0.f, 0.f, 0.f};
#pragma unroll
    for (int mi = 0; mi < 2; ++mi) {
        int rbase = row0 + wm * 32 + mi * 16 + (lane >> 4) * 4;
#pragma unroll
        for (int ni = 0; ni < 4; ++ni) {
            int col = col0 + wn * 64 + ni * 16 + (lane & 15);
            float b = BIAS ? bias[col] : 0.f;
#pragma unroll
            for (int r = 0; r < 4; ++r) {
                int row = rbase + r;
                if (row < NN) {
                    float v = acc[mi][ni][r] + b;
                    if constexpr (STATS) { psum[ni] += v; psq[ni] = fmaf(v, v, psq[ni]); }
                    if constexpr (OSPLIT) {
                        unsigned short hi = f2bf(v);
                        OHs[(size_t)row * NCOLS + col] = hi;
                        OLs[(size_t)row * NCOLS + col] = f2bf(v - bf2f(hi));
                    } else {
                        C[(size_t)row * NCOLS + col] = v;
                    }
                }
            }
        }
    }

    if constexpr (STATS) {
        __shared__ float s_sum[128], s_sq[128];
        if (tid < 128) { s_sum[tid] = 0.f; s_sq[tid] = 0.f; }
        __syncthreads();
#pragma unroll
        for (int ni = 0; ni < 4; ++ni) {
            float a = psum[ni], q = psq[ni];
            a += __shfl_xor(a, 16); a += __shfl_xor(a, 32);
            q += __shfl_xor(q, 16); q += __shfl_xor(q, 32);
            if ((lane >> 4) == 0) {
                int cl = wn * 64 + ni * 16 + lane;   // lane < 16 here
                atomicAdd(&s_sum[cl], a);
                atomicAdd(&s_sq[cl], q);
            }
        }
        __syncthreads();
        if (tid < 128) {
            atomicAdd(&statsOut[col0 + tid], s_sum[tid]);
            atomicAdd(&statsOut[256 + col0 + tid], s_sq[tid]);
        }
    }
}

extern "C" void kernel_launch(void* const* d_in, const int* in_sizes, int n_in,
                              void* d_out, int out_size, void* d_ws, size_t ws_size,
                              hipStream_t stream) {
    const float* feat  = (const float*)d_in[0];
    const int*   src   = (const int*)d_in[1];
    const int*   dst   = (const int*)d_in[2];
    const float* W0    = (const float*)d_in[3];
    const float* W1    = (const float*)d_in[4];
    const float* Wp1   = (const float*)d_in[5];
    const float* bp1   = (const float*)d_in[6];
    const float* gamma = (const float*)d_in[7];
    const float* beta  = (const float*)d_in[8];
    const float* Wp2   = (const float*)d_in[9];
    const float* bp2   = (const float*)d_in[10];
    float* out = (float*)d_out;

    char* wsb = (char*)d_ws;
    float* dinv   = (float*)(wsb + 4ull * 0);
    int*   cnt    = (int*)  (wsb + 4ull * 50048);     // cnt+cursor adjacent: 1 memset
    int*   cursor = (int*)  (wsb + 4ull * 100096);
    int*   rowoff = (int*)  (wsb + 4ull * 150144);
    int*   bsum   = (int*)  (wsb + 4ull * 200192);
    int*   boff   = (int*)  (wsb + 4ull * 200448);
    int*   eidx   = (int*)  (wsb + 4ull * 200704);
    float* stats  = (float*)(wsb + 4ull * 1000704);
    float* W1p    = (float*)(wsb + 4ull * 1001728);          // [128][256] fp32
    unsigned short* W0tH  = (unsigned short*)(wsb + 4ull * 1034496);
    unsigned short* W0tL  = W0tH + 65536;
    unsigned short* W1ptH = W0tL + 65536;
    unsigned short* W1ptL = W1ptH + 32768;
    unsigned short* Wp2tH = W1ptL + 32768;
    unsigned short* Wp2tL = Wp2tH + 32768;                   // ends word 1165568
    // flat H buffers: [NNP][128] u16 each (3203072 words apiece)
    unsigned short* H0H = (unsigned short*)(wsb + 4ull * 1165568);
    unsigned short* H0L = (unsigned short*)(wsb + 4ull * 4368640);
    unsigned short* h1H = (unsigned short*)(wsb + 4ull * 7571712);
    unsigned short* h1L = (unsigned short*)(wsb + 4ull * 10774784);
    unsigned short* h2H = H0H;   // reuse after H0 consumed
    unsigned short* h2L = H0L;
    float* Z = (float*)(wsb + 4ull * 13977856);              // [NN][256] fp32

    const int GX = NNP / 128;  // 391

    // ---- CSR build ----
    hipMemsetAsync(cnt, 0, 2 * 50048 * sizeof(int), stream);   // cnt + cursor
    k_count<<<(NE + 255) / 256, 256, 0, stream>>>(dst, cnt);
    k_bsum<<<NB, 256, 0, stream>>>(cnt, bsum);
    k_scan_bsum<<<1, 256, 0, stream>>>(bsum, boff);
    k_scan_block<<<NB, 256, 0, stream>>>(cnt, boff, rowoff, dinv);
    k_fill<<<(NE + 255) / 256, 256, 0, stream>>>(src, dst, rowoff, cursor, eidx);

    // ---- weight prep (2 launches; k_mm128 also zeroes stats) ----
    k_mm128<<<128, 256, 0, stream>>>(W1, Wp1, W1p, stats);     // W1p = W1 @ Wp1
    k_wsplit_all<<<512, 256, 0, stream>>>(W0, W1p, Wp2, W0tH, W0tL,
                                          W1ptH, W1ptL, Wp2tH, Wp2tL);

    // H0 = feat @ W0  (A fp32 reg-staged, B split 2-pass, flat hi/lo output)
    k_mfma<512, 128, false, false, true, 1, true, false><<<dim3(GX, 1), 512, 0, stream>>>(
        nullptr, nullptr, feat, W0tH, W0tL, nullptr, nullptr, nullptr, nullptr,
        nullptr, H0H, H0L, nullptr);

    // h1 = conv(H0); h2 = conv(h1)   [conv commutes with right-mult by W]
    k_gather4<<<NNP / 4, 256, 0, stream>>>(H0H, H0L, dinv, rowoff, cnt, eidx, h1H, h1L);
    k_gather4<<<NNP / 4, 256, 0, stream>>>(h1H, h1L, dinv, rowoff, cnt, eidx, h2H, h2L);

    // Z = h2 @ (W1@Wp1) + bp1  [NN,256], fused BN column stats (3-pass)
    k_mfma<128, 256, true, true, true, 0, false, true><<<dim3(GX, 2), 512, 0, stream>>>(
        h2H, h2L, nullptr, W1ptH, W1ptL, bp1, nullptr, nullptr, nullptr,
        Z, nullptr, nullptr, stats);

    // out = relu(BN(Z)) @ Wp2 + bp2  (bnprep fused into A staging; B single pass)
    k_mfma<256, 128, true, false, false, 2, false, false><<<dim3(GX, 1), 512, 0, stream>>>(
        nullptr, nullptr, Z, Wp2tH, nullptr, bp2, stats, gamma, beta,
        out, nullptr, nullptr, nullptr);
}

// Round 8
// 253.791 us; speedup vs baseline: 1.6467x; 1.0650x over previous
//
#include <hip/hip_runtime.h>
#include <math.h>

constexpr int NN  = 50000;
constexpr int NE  = 800000;
constexpr int NNP = 50048;             // padded rows = 391 * 128
constexpr int NB  = (NN + 255) / 256;  // scan blocks

typedef __bf16 bf16x8 __attribute__((ext_vector_type(8)));
typedef float  f32x4  __attribute__((ext_vector_type(4)));
typedef __attribute__((address_space(1))) unsigned int as1_uint;
typedef __attribute__((address_space(3))) unsigned int as3_uint;

__device__ __forceinline__ unsigned short f2bf(float x) {  // RNE fp32->bf16 bits
    unsigned int u = __float_as_uint(x);
    return (unsigned short)((u + 0x7FFFu + ((u >> 16) & 1u)) >> 16);
}
__device__ __forceinline__ float bf2f(unsigned short h) {
    return __uint_as_float(((unsigned int)h) << 16);
}
__device__ __forceinline__ float rdlanef(float v, int j) {
    return __uint_as_float(__builtin_amdgcn_readlane(__float_as_uint(v), j));
}

__device__ __forceinline__ void gload16(const unsigned short* g, unsigned short* l) {
    __builtin_amdgcn_global_load_lds((const as1_uint*)(unsigned long long)g,
                                     (as3_uint*)(unsigned long long)l, 16, 0, 0);
}

// ---------------- CSR build ----------------
__global__ void k_count(const int* __restrict__ dst, int* __restrict__ cnt) {
    int i = blockIdx.x * blockDim.x + threadIdx.x;
    if (i < NE) atomicAdd(&cnt[dst[i]], 1);
}

__global__ void k_bsum(const int* __restrict__ cnt, int* __restrict__ bsum) {
    int i = blockIdx.x * 256 + threadIdx.x;
    int v = (i < NN) ? cnt[i] : 0;
#pragma unroll
    for (int off = 32; off; off >>= 1) v += __shfl_down(v, off, 64);
    __shared__ int tmp[4];
    if ((threadIdx.x & 63) == 0) tmp[threadIdx.x >> 6] = v;
    __syncthreads();
    if (threadIdx.x == 0) bsum[blockIdx.x] = tmp[0] + tmp[1] + tmp[2] + tmp[3];
}

__global__ void k_scan_bsum(const int* __restrict__ bsum, int* __restrict__ boff) {
    __shared__ int s[256];
    int t = threadIdx.x;
    int v = (t < NB) ? bsum[t] : 0;
    s[t] = v;
    __syncthreads();
    for (int off = 1; off < 256; off <<= 1) {
        int u = (t >= off) ? s[t - off] : 0;
        __syncthreads();
        s[t] += u;
        __syncthreads();
    }
    if (t < NB) boff[t] = s[t] - v;
}

// also emits dinv (folded k_dinv)
__global__ void k_scan_block(const int* __restrict__ cnt, const int* __restrict__ boff,
                             int* __restrict__ rowoff, float* __restrict__ dinv) {
    __shared__ int s[256];
    int t = threadIdx.x;
    int i = blockIdx.x * 256 + t;
    int v = (i < NN) ? cnt[i] : 0;
    s[t] = v;
    __syncthreads();
    for (int off = 1; off < 256; off <<= 1) {
        int u = (t >= off) ? s[t - off] : 0;
        __syncthreads();
        s[t] += u;
        __syncthreads();
    }
    if (i < NN) {
        rowoff[i] = boff[blockIdx.x] + s[t] - v;
        dinv[i] = rsqrtf(fmaxf((float)v, 1.0f));
    }
}

__global__ void k_fill(const int* __restrict__ src, const int* __restrict__ dst,
                       const int* __restrict__ rowoff, int* __restrict__ cursor,
                       int* __restrict__ eidx) {
    int e = blockIdx.x * blockDim.x + threadIdx.x;
    if (e < NE) {
        int d = dst[e];
        int p = atomicAdd(&cursor[d], 1);
        eidx[rowoff[d] + p] = src[e];
    }
}

// ---------------- shfl-broadcast low_conv gather ----------------
// wave = 1 node, all 64 lanes on one row (ushort2/lane = full 256B row per load).
// eidx+dinv preloaded lane-parallel, broadcast via readlane -> per-edge critical
// path is just the row load. unroll x4 = 4 independent rows in flight.
__global__ __launch_bounds__(256) void k_gather_shfl(
    const unsigned short* __restrict__ HH, const unsigned short* __restrict__ HL,
    const float* __restrict__ dinv, const int* __restrict__ rowoff,
    const int* __restrict__ cnt, const int* __restrict__ eidx,
    unsigned short* __restrict__ OH, unsigned short* __restrict__ OL)
{
    int node = blockIdx.x * 4 + (threadIdx.x >> 6);
    int lane = threadIdx.x & 63;
    if (node >= NNP) return;
    size_t rb = (size_t)node * 128 + lane * 2;
    if (node >= NN) {  // zero pad rows
        *reinterpret_cast<ushort2*>(&OH[rb]) = make_ushort2(0, 0);
        *reinterpret_cast<ushort2*>(&OL[rb]) = make_ushort2(0, 0);
        return;
    }
    int beg = rowoff[node], n = cnt[node];
    int c2 = lane * 2;
    float ax = 0.f, ay = 0.f;
    for (int jj = 0; jj < n; jj += 64) {
        int m = min(n - jj, 64);
        int el = (lane < m) ? eidx[beg + jj + lane] : 0;
        float dl = dinv[el];
        int j = 0;
        for (; j + 4 <= m; j += 4) {
            int s0 = __builtin_amdgcn_readlane(el, j);
            int s1 = __builtin_amdgcn_readlane(el, j + 1);
            int s2 = __builtin_amdgcn_readlane(el, j + 2);
            int s3 = __builtin_amdgcn_readlane(el, j + 3);
            float d0 = rdlanef(dl, j),     d1 = rdlanef(dl, j + 1);
            float d2 = rdlanef(dl, j + 2), d3 = rdlanef(dl, j + 3);
            ushort2 v0 = *reinterpret_cast<const ushort2*>(&HH[(size_t)s0 * 128 + c2]);
            ushort2 v1 = *reinterpret_cast<const ushort2*>(&HH[(size_t)s1 * 128 + c2]);
            ushort2 v2 = *reinterpret_cast<const ushort2*>(&HH[(size_t)s2 * 128 + c2]);
            ushort2 v3 = *reinterpret_cast<const ushort2*>(&HH[(size_t)s3 * 128 + c2]);
            ax = fmaf(bf2f(v0.x), d0, ax); ay = fmaf(bf2f(v0.y), d0, ay);
            ax = fmaf(bf2f(v1.x), d1, ax); ay = fmaf(bf2f(v1.y), d1, ay);
            ax = fmaf(bf2f(v2.x), d2, ax); ay = fmaf(bf2f(v2.y), d2, ay);
            ax = fmaf(bf2f(v3.x), d3, ax); ay = fmaf(bf2f(v3.y), d3, ay);
        }
        for (; j < m; ++j) {
            int s0 = __builtin_amdgcn_readlane(el, j);
            float d0 = rdlanef(dl, j);
            ushort2 v0 = *reinterpret_cast<const ushort2*>(&HH[(size_t)s0 * 128 + c2]);
            ax = fmaf(bf2f(v0.x), d0, ax); ay = fmaf(bf2f(v0.y), d0, ay);
        }
    }
    float d = dinv[node];
    ushort2 sh = *reinterpret_cast<const ushort2*>(&HH[rb]);
    ushort2 sl = *reinterpret_cast<const ushort2*>(&HL[rb]);
    float hx = fmaf(ax, d, bf2f(sh.x) + bf2f(sl.x));
    float hy = fmaf(ay, d, bf2f(sh.y) + bf2f(sl.y));
    ushort2 hv, lv;
    hv.x = f2bf(hx); lv.x = f2bf(hx - bf2f(hv.x));
    hv.y = f2bf(hy); lv.y = f2bf(hy - bf2f(hv.y));
    *reinterpret_cast<ushort2*>(&OH[rb]) = hv;
    *reinterpret_cast<ushort2*>(&OL[rb]) = lv;
}

// ---------------- unified weight prep (1 launch, 512 blocks) ----------------
// blocks 0..127:   W1p = W1@Wp1 row i, split directly to W1pt[N=256][K=128] (+zero stats)
// blocks 128..383: W0 [512][128] -> W0t [128][512] hi/lo
// blocks 384..511: Wp2 [256][128] -> Wp2t [128][256] hi/lo
__global__ void k_wprep(const float* __restrict__ W0, const float* __restrict__ W1,
                        const float* __restrict__ Wp1, const float* __restrict__ Wp2,
                        unsigned short* __restrict__ W0tH, unsigned short* __restrict__ W0tL,
                        unsigned short* __restrict__ W1ptH, unsigned short* __restrict__ W1ptL,
                        unsigned short* __restrict__ Wp2tH, unsigned short* __restrict__ Wp2tL,
                        float* __restrict__ stats) {
    int b = blockIdx.x, t = threadIdx.x;
    if (b < 128) {
        if (b < 2) stats[b * 256 + t] = 0.f;
        float s = 0.f;
        for (int k = 0; k < 128; ++k) s = fmaf(W1[b * 128 + k], Wp1[k * 256 + t], s);
        unsigned short hi = f2bf(s);
        W1ptH[t * 128 + b] = hi;
        W1ptL[t * 128 + b] = f2bf(s - bf2f(hi));
    } else if (b < 384) {
        int idx = (b - 128) * 256 + t;     // W0: K=512, N=128
        int k = idx >> 7, n = idx & 127;
        float a = W0[idx];
        unsigned short hi = f2bf(a);
        W0tH[n * 512 + k] = hi;
        W0tL[n * 512 + k] = f2bf(a - bf2f(hi));
    } else {
        int idx = (b - 384) * 256 + t;     // Wp2: K=256, N=128
        int k = idx >> 7, n = idx & 127;
        float a = Wp2[idx];
        unsigned short hi = f2bf(a);
        Wp2tH[n * 256 + k] = hi;
        Wp2tL[n * 256 + k] = f2bf(a - bf2f(hi));
    }
}

// ---------------- split-precision MFMA GEMM (flat layouts) ----------------
// AMODE: 0 = bf16 hi(/lo) via global_load_lds; 1 = fp32 reg-staged -> bf16;
//        2 = bf16-hi reg-staged + BN(from raw stats/gamma/beta)+ReLU -> bf16.
// BLO: include B-lo pass. OMODE: 0 = fp32 C; 1 = bf16 hi/lo; 2 = bf16 hi only
// (pad rows written too). STATS: column sum/sumsq over rows < NN.
template <int K, int NCOLS, bool BIAS, bool ALO, bool BLO, int AMODE, int OMODE, bool STATS>
__global__ __launch_bounds__(512) void k_mfma(
    const unsigned short* __restrict__ AH, const unsigned short* __restrict__ AL,
    const float* __restrict__ Af,
    const unsigned short* __restrict__ BH, const unsigned short* __restrict__ BL,
    const float* __restrict__ bias,
    const float* __restrict__ stats, const float* __restrict__ gamma,
    const float* __restrict__ beta,
    float* __restrict__ C, unsigned short* __restrict__ OHs, unsigned short* __restrict__ OLs,
    float* __restrict__ statsOut)
{
    __shared__ __align__(16) unsigned short lds[4 * 4096];
    unsigned short* ldsAH = lds;
    unsigned short* ldsAL = lds + 4096;
    unsigned short* ldsBH = lds + 8192;
    unsigned short* ldsBL = lds + 12288;

    const int tid  = threadIdx.x;
    const int lane = tid & 63;
    const int wid  = tid >> 6;
    const int wm   = wid >> 1;
    const int wn   = wid & 1;
    const int row0 = blockIdx.x * 128;
    const int col0 = blockIdx.y * 128;

    const int srow  = tid >> 2;
    const int skg   = tid & 3;
    const int skswz = skg ^ ((srow >> 1) & 3);  // inverse swizzle on SOURCE
    const size_t aSrc = (size_t)(row0 + srow) * K + skswz * 8;
    const size_t bSrc = (size_t)(col0 + srow) * K + skswz * 8;

    const int frow = lane & 15;
    const int fkg  = lane >> 4;

    f32x4 acc[2][4] = {};

    for (int k0 = 0; k0 < K; k0 += 32) {
        if constexpr (AMODE == 1) {
            float4 f0, f1;
            if (row0 + srow < NN) {
                const float* ap = Af + aSrc + k0;
                f0 = *reinterpret_cast<const float4*>(ap);
                f1 = *reinterpret_cast<const float4*>(ap + 4);
            } else {
                f0 = make_float4(0.f, 0.f, 0.f, 0.f);
                f1 = f0;
            }
            uint4 w;
            w.x = (unsigned)f2bf(f0.x) | ((unsigned)f2bf(f0.y) << 16);
            w.y = (unsigned)f2bf(f0.z) | ((unsigned)f2bf(f0.w) << 16);
            w.z = (unsigned)f2bf(f1.x) | ((unsigned)f2bf(f1.y) << 16);
            w.w = (unsigned)f2bf(f1.z) | ((unsigned)f2bf(f1.w) << 16);
            *reinterpret_cast<uint4*>(&ldsAH[tid * 8]) = w;
        } else if constexpr (AMODE == 2) {
            // bf16-hi input + fused BN(raw stats)+ReLU -> bf16
            uint4 raw = *reinterpret_cast<const uint4*>(&AH[aSrc + k0]);
            unsigned rw[4] = {raw.x, raw.y, raw.z, raw.w};
            int kc = k0 + skswz * 8;
            float vv[8];
#pragma unroll
            for (int q = 0; q < 8; ++q) {
                float z = bf2f((unsigned short)((q & 1) ? (rw[q >> 1] >> 16)
                                                        : (rw[q >> 1] & 0xFFFF)));
                int kcol = kc + q;
                float mu  = stats[kcol] * (1.0f / NN);
                float var = stats[256 + kcol] * (1.0f / NN) - mu * mu;
                float s = gamma[kcol] * rsqrtf(var + 1e-5f);
                vv[q] = fmaxf(fmaf(z - mu, s, beta[kcol]), 0.f);
            }
            uint4 w;
            w.x = (unsigned)f2bf(vv[0]) | ((unsigned)f2bf(vv[1]) << 16);
            w.y = (unsigned)f2bf(vv[2]) | ((unsigned)f2bf(vv[3]) << 16);
            w.z = (unsigned)f2bf(vv[4]) | ((unsigned)f2bf(vv[5]) << 16);
            w.w = (unsigned)f2bf(vv[6]) | ((unsigned)f2bf(vv[7]) << 16);
            *reinterpret_cast<uint4*>(&ldsAH[tid * 8]) = w;
        } else {
            gload16(AH + aSrc + k0, ldsAH + tid * 8);
            if constexpr (ALO) gload16(AL + aSrc + k0, ldsAL + tid * 8);
        }
        gload16(BH + bSrc + k0, ldsBH + tid * 8);
        if constexpr (BLO) gload16(BL + bSrc + k0, ldsBL + tid * 8);
        __syncthreads();

        bf16x8 a_h[2], a_l[2], b_h[4], b_l[4];
#pragma unroll
        for (int mi = 0; mi < 2; ++mi) {
            int ar  = wm * 32 + mi * 16 + frow;
            int idx = ar * 32 + ((fkg ^ ((ar >> 1) & 3)) * 8);
            a_h[mi] = *reinterpret_cast<const bf16x8*>(&ldsAH[idx]);
            if constexpr (ALO) a_l[mi] = *reinterpret_cast<const bf16x8*>(&ldsAL[idx]);
        }
#pragma unroll
        for (int ni = 0; ni < 4; ++ni) {
            int bc  = wn * 64 + ni * 16 + frow;
            int idx = bc * 32 + ((fkg ^ ((bc >> 1) & 3)) * 8);
            b_h[ni] = *reinterpret_cast<const bf16x8*>(&ldsBH[idx]);
            if constexpr (BLO) b_l[ni] = *reinterpret_cast<const bf16x8*>(&ldsBL[idx]);
        }
#pragma unroll
        for (int mi = 0; mi < 2; ++mi)
#pragma unroll
            for (int ni = 0; ni < 4; ++ni) {
                acc[mi][ni] = __builtin_amdgcn_mfma_f32_16x16x32_bf16(a_h[mi], b_h[ni], acc[mi][ni], 0, 0, 0);
                if constexpr (BLO)
                    acc[mi][ni] = __builtin_amdgcn_mfma_f32_16x16x32_bf16(a_h[mi], b_l[ni], acc[mi][ni], 0, 0, 0);
                if constexpr (ALO)
                    acc[mi][ni] = __builtin_amdgcn_mfma_f32_16x16x32_bf16(a_l[mi], b_h[ni], acc[mi][ni], 0, 0, 0);
            }
        __syncthreads();
    }

    float psum[4] = {0.f, 0.f, 0.f, 0.f}, psq[4] = {0.f, 0.f, 0.f, 0.f};
#pragma unroll
    for (int mi = 0; mi < 2; ++mi) {
        int rbase = row0 + wm * 32 + mi * 16 + (lane >> 4) * 4;
#pragma unroll
        for (int ni = 0; ni < 4; ++ni) {
            int col = col0 + wn * 64 + ni * 16 + (lane & 15);
            float b = BIAS ? bias[col] : 0.f;
#pragma unroll
            for (int r = 0; r < 4; ++r) {
                int row = rbase + r;
                float v = acc[mi][ni][r] + b;
                if constexpr (STATS) {
                    if (row < NN) { psum[ni] += v; psq[ni] = fmaf(v, v, psq[ni]); }
                }
                if constexpr (OMODE == 2) {
                    OHs[(size_t)row * NCOLS + col] = f2bf(v);   // pad rows too
                } else if constexpr (OMODE == 1) {
                    if (row < NN) {
                        unsigned short hi = f2bf(v);
                        OHs[(size_t)row * NCOLS + col] = hi;
                        OLs[(size_t)row * NCOLS + col] = f2bf(v - bf2f(hi));
                    }
                } else {
                    if (row < NN) C[(size_t)row * NCOLS + col] = v;
                }
            }
        }
    }

    if constexpr (STATS) {
        __shared__ float s_sum[128], s_sq[128];
        if (tid < 128) { s_sum[tid] = 0.f; s_sq[tid] = 0.f; }
        __syncthreads();
#pragma unroll
        for (int ni = 0; ni < 4; ++ni) {
            float a = psum[ni], q = psq[ni];
            a += __shfl_xor(a, 16); a += __shfl_xor(a, 32);
            q += __shfl_xor(q, 16); q += __shfl_xor(q, 32);
            if ((lane >> 4) == 0) {
                int cl = wn * 64 + ni * 16 + lane;   // lane < 16 here
                atomicAdd(&s_sum[cl], a);
                atomicAdd(&s_sq[cl], q);
            }
        }
        __syncthreads();
        if (tid < 128) {
            atomicAdd(&statsOut[col0 + tid], s_sum[tid]);
            atomicAdd(&statsOut[256 + col0 + tid], s_sq[tid]);
        }
    }
}

extern "C" void kernel_launch(void* const* d_in, const int* in_sizes, int n_in,
                              void* d_out, int out_size, void* d_ws, size_t ws_size,
                              hipStream_t stream) {
    const float* feat  = (const float*)d_in[0];
    const int*   src   = (const int*)d_in[1];
    const int*   dst   = (const int*)d_in[2];
    const float* W0    = (const float*)d_in[3];
    const float* W1    = (const float*)d_in[4];
    const float* Wp1   = (const float*)d_in[5];
    const float* bp1   = (const float*)d_in[6];
    const float* gamma = (const float*)d_in[7];
    const float* beta  = (const float*)d_in[8];
    const float* Wp2   = (const float*)d_in[9];
    const float* bp2   = (const float*)d_in[10];
    float* out = (float*)d_out;

    char* wsb = (char*)d_ws;
    float* dinv   = (float*)(wsb + 4ull * 0);
    int*   cnt    = (int*)  (wsb + 4ull * 50048);     // cnt+cursor adjacent: 1 memset
    int*   cursor = (int*)  (wsb + 4ull * 100096);
    int*   rowoff = (int*)  (wsb + 4ull * 150144);
    int*   bsum   = (int*)  (wsb + 4ull * 200192);
    int*   boff   = (int*)  (wsb + 4ull * 200448);
    int*   eidx   = (int*)  (wsb + 4ull * 200704);
    float* stats  = (float*)(wsb + 4ull * 1000704);
    unsigned short* W0tH  = (unsigned short*)(wsb + 4ull * 1034496);
    unsigned short* W0tL  = W0tH + 65536;
    unsigned short* W1ptH = W0tL + 65536;
    unsigned short* W1ptL = W1ptH + 32768;
    unsigned short* Wp2tH = W1ptL + 32768;
    unsigned short* Wp2tL = Wp2tH + 32768;                   // ends word 1165568
    // flat H buffers: [NNP][128] u16 each (3203072 words apiece)
    unsigned short* H0H = (unsigned short*)(wsb + 4ull * 1165568);
    unsigned short* H0L = (unsigned short*)(wsb + 4ull * 4368640);
    unsigned short* h1H = (unsigned short*)(wsb + 4ull * 7571712);
    unsigned short* h1L = (unsigned short*)(wsb + 4ull * 10774784);
    unsigned short* h2H = H0H;   // reuse after H0 consumed
    unsigned short* h2L = H0L;
    unsigned short* ZH = (unsigned short*)(wsb + 4ull * 13977856);   // [NNP][256] u16

    const int GX = NNP / 128;  // 391

    // ---- CSR build ----
    hipMemsetAsync(cnt, 0, 2 * 50048 * sizeof(int), stream);   // cnt + cursor
    k_count<<<(NE + 255) / 256, 256, 0, stream>>>(dst, cnt);
    k_bsum<<<NB, 256, 0, stream>>>(cnt, bsum);
    k_scan_bsum<<<1, 256, 0, stream>>>(bsum, boff);
    k_scan_block<<<NB, 256, 0, stream>>>(cnt, boff, rowoff, dinv);
    k_fill<<<(NE + 255) / 256, 256, 0, stream>>>(src, dst, rowoff, cursor, eidx);

    // ---- weight prep (1 launch; also zeroes stats) ----
    k_wprep<<<512, 256, 0, stream>>>(W0, W1, Wp1, Wp2, W0tH, W0tL,
                                     W1ptH, W1ptL, Wp2tH, Wp2tL, stats);

    // H0 = feat @ W0  (A fp32 reg-staged, B split 2-pass, flat hi/lo output)
    k_mfma<512, 128, false, false, true, 1, 1, false><<<dim3(GX, 1), 512, 0, stream>>>(
        nullptr, nullptr, feat, W0tH, W0tL, nullptr, nullptr, nullptr, nullptr,
        nullptr, H0H, H0L, nullptr);

    // h1 = conv(H0); h2 = conv(h1)   [conv commutes with right-mult by W]
    k_gather_shfl<<<NNP / 4, 256, 0, stream>>>(H0H, H0L, dinv, rowoff, cnt, eidx, h1H, h1L);
    k_gather_shfl<<<NNP / 4, 256, 0, stream>>>(h1H, h1L, dinv, rowoff, cnt, eidx, h2H, h2L);

    // Z = h2 @ (W1@Wp1) + bp1  [NNP,256] bf16-hi, fused BN column stats (3-pass)
    k_mfma<128, 256, true, true, true, 0, 2, true><<<dim3(GX, 2), 512, 0, stream>>>(
        h2H, h2L, nullptr, W1ptH, W1ptL, bp1, nullptr, nullptr, nullptr,
        nullptr, ZH, nullptr, stats);

    // out = relu(BN(Z)) @ Wp2 + bp2  (bf16 Z + fused bnprep in A staging; B 1-pass)
    k_mfma<256, 128, true, false, false, 2, 0, false><<<dim3(GX, 1), 512, 0, stream>>>(
        ZH, nullptr, nullptr, Wp2tH, nullptr, bp2, stats, gamma, beta,
        out, nullptr, nullptr, nullptr);
}

// Round 9
// 237.690 us; speedup vs baseline: 1.7582x; 1.0677x over previous
//
#include <hip/hip_runtime.h>
#include <math.h>

constexpr int NN  = 50000;
constexpr int NE  = 800000;
constexpr int NNP = 50048;             // padded rows = 391 * 128
constexpr int NB  = (NN + 255) / 256;  // scan blocks

typedef __bf16 bf16x8 __attribute__((ext_vector_type(8)));
typedef float  f32x4  __attribute__((ext_vector_type(4)));
typedef __attribute__((address_space(1))) unsigned int as1_uint;
typedef __attribute__((address_space(3))) unsigned int as3_uint;

__device__ __forceinline__ unsigned short f2bf(float x) {  // RNE fp32->bf16 bits
    unsigned int u = __float_as_uint(x);
    return (unsigned short)((u + 0x7FFFu + ((u >> 16) & 1u)) >> 16);
}
__device__ __forceinline__ float bf2f(unsigned short h) {
    return __uint_as_float(((unsigned int)h) << 16);
}
__device__ __forceinline__ float rdlanef(float v, int j) {
    return __uint_as_float(__builtin_amdgcn_readlane(__float_as_uint(v), j));
}

__device__ __forceinline__ void gload16(const unsigned short* g, unsigned short* l) {
    __builtin_amdgcn_global_load_lds((const as1_uint*)(unsigned long long)g,
                                     (as3_uint*)(unsigned long long)l, 16, 0, 0);
}

// ---------------- CSR build ----------------
__global__ void k_count(const int* __restrict__ dst, int* __restrict__ cnt) {
    int i = blockIdx.x * blockDim.x + threadIdx.x;
    if (i < NE) atomicAdd(&cnt[dst[i]], 1);
}

__global__ void k_bsum(const int* __restrict__ cnt, int* __restrict__ bsum) {
    int i = blockIdx.x * 256 + threadIdx.x;
    int v = (i < NN) ? cnt[i] : 0;
#pragma unroll
    for (int off = 32; off; off >>= 1) v += __shfl_down(v, off, 64);
    __shared__ int tmp[4];
    if ((threadIdx.x & 63) == 0) tmp[threadIdx.x >> 6] = v;
    __syncthreads();
    if (threadIdx.x == 0) bsum[blockIdx.x] = tmp[0] + tmp[1] + tmp[2] + tmp[3];
}

__global__ void k_scan_bsum(const int* __restrict__ bsum, int* __restrict__ boff) {
    __shared__ int s[256];
    int t = threadIdx.x;
    int v = (t < NB) ? bsum[t] : 0;
    s[t] = v;
    __syncthreads();
    for (int off = 1; off < 256; off <<= 1) {
        int u = (t >= off) ? s[t - off] : 0;
        __syncthreads();
        s[t] += u;
        __syncthreads();
    }
    if (t < NB) boff[t] = s[t] - v;
}

// also emits dinv (folded k_dinv)
__global__ void k_scan_block(const int* __restrict__ cnt, const int* __restrict__ boff,
                             int* __restrict__ rowoff, float* __restrict__ dinv) {
    __shared__ int s[256];
    int t = threadIdx.x;
    int i = blockIdx.x * 256 + t;
    int v = (i < NN) ? cnt[i] : 0;
    s[t] = v;
    __syncthreads();
    for (int off = 1; off < 256; off <<= 1) {
        int u = (t >= off) ? s[t - off] : 0;
        __syncthreads();
        s[t] += u;
        __syncthreads();
    }
    if (i < NN) {
        rowoff[i] = boff[blockIdx.x] + s[t] - v;
        dinv[i] = rsqrtf(fmaxf((float)v, 1.0f));
    }
}

__global__ void k_fill(const int* __restrict__ src, const int* __restrict__ dst,
                       const int* __restrict__ rowoff, int* __restrict__ cursor,
                       int* __restrict__ eidx) {
    int e = blockIdx.x * blockDim.x + threadIdx.x;
    if (e < NE) {
        int d = dst[e];
        int p = atomicAdd(&cursor[d], 1);
        eidx[rowoff[d] + p] = src[e];
    }
}

// ---------------- shfl-broadcast low_conv gather (single bf16) ----------------
// wave = 1 node, 64 lanes x ushort2 = full 256B row per load instruction.
// eidx+dinv preloaded lane-parallel, broadcast via readlane. unroll x8.
__global__ __launch_bounds__(256) void k_gather_shfl(
    const unsigned short* __restrict__ HH, const float* __restrict__ dinv,
    const int* __restrict__ rowoff, const int* __restrict__ cnt,
    const int* __restrict__ eidx, unsigned short* __restrict__ OH)
{
    int node = blockIdx.x * 4 + (threadIdx.x >> 6);
    int lane = threadIdx.x & 63;
    if (node >= NNP) return;
    size_t rb = (size_t)node * 128 + lane * 2;
    if (node >= NN) {  // zero pad rows
        *reinterpret_cast<ushort2*>(&OH[rb]) = make_ushort2(0, 0);
        return;
    }
    int beg = rowoff[node], n = cnt[node];
    int c2 = lane * 2;
    float ax = 0.f, ay = 0.f;
    for (int jj = 0; jj < n; jj += 64) {
        int m = min(n - jj, 64);
        int el = (lane < m) ? eidx[beg + jj + lane] : 0;
        float dl = dinv[el];
        int j = 0;
        for (; j + 8 <= m; j += 8) {   // 8 independent row loads in flight
            int s0 = __builtin_amdgcn_readlane(el, j);
            int s1 = __builtin_amdgcn_readlane(el, j + 1);
            int s2 = __builtin_amdgcn_readlane(el, j + 2);
            int s3 = __builtin_amdgcn_readlane(el, j + 3);
            int s4 = __builtin_amdgcn_readlane(el, j + 4);
            int s5 = __builtin_amdgcn_readlane(el, j + 5);
            int s6 = __builtin_amdgcn_readlane(el, j + 6);
            int s7 = __builtin_amdgcn_readlane(el, j + 7);
            ushort2 v0 = *reinterpret_cast<const ushort2*>(&HH[(size_t)s0 * 128 + c2]);
            ushort2 v1 = *reinterpret_cast<const ushort2*>(&HH[(size_t)s1 * 128 + c2]);
            ushort2 v2 = *reinterpret_cast<const ushort2*>(&HH[(size_t)s2 * 128 + c2]);
            ushort2 v3 = *reinterpret_cast<const ushort2*>(&HH[(size_t)s3 * 128 + c2]);
            ushort2 v4 = *reinterpret_cast<const ushort2*>(&HH[(size_t)s4 * 128 + c2]);
            ushort2 v5 = *reinterpret_cast<const ushort2*>(&HH[(size_t)s5 * 128 + c2]);
            ushort2 v6 = *reinterpret_cast<const ushort2*>(&HH[(size_t)s6 * 128 + c2]);
            ushort2 v7 = *reinterpret_cast<const ushort2*>(&HH[(size_t)s7 * 128 + c2]);
            float d0 = rdlanef(dl, j),     d1 = rdlanef(dl, j + 1);
            float d2 = rdlanef(dl, j + 2), d3 = rdlanef(dl, j + 3);
            float d4 = rdlanef(dl, j + 4), d5 = rdlanef(dl, j + 5);
            float d6 = rdlanef(dl, j + 6), d7 = rdlanef(dl, j + 7);
            ax = fmaf(bf2f(v0.x), d0, ax); ay = fmaf(bf2f(v0.y), d0, ay);
            ax = fmaf(bf2f(v1.x), d1, ax); ay = fmaf(bf2f(v1.y), d1, ay);
            ax = fmaf(bf2f(v2.x), d2, ax); ay = fmaf(bf2f(v2.y), d2, ay);
            ax = fmaf(bf2f(v3.x), d3, ax); ay = fmaf(bf2f(v3.y), d3, ay);
            ax = fmaf(bf2f(v4.x), d4, ax); ay = fmaf(bf2f(v4.y), d4, ay);
            ax = fmaf(bf2f(v5.x), d5, ax); ay = fmaf(bf2f(v5.y), d5, ay);
            ax = fmaf(bf2f(v6.x), d6, ax); ay = fmaf(bf2f(v6.y), d6, ay);
            ax = fmaf(bf2f(v7.x), d7, ax); ay = fmaf(bf2f(v7.y), d7, ay);
        }
        for (; j < m; ++j) {
            int s0 = __builtin_amdgcn_readlane(el, j);
            float d0 = rdlanef(dl, j);
            ushort2 v0 = *reinterpret_cast<const ushort2*>(&HH[(size_t)s0 * 128 + c2]);
            ax = fmaf(bf2f(v0.x), d0, ax); ay = fmaf(bf2f(v0.y), d0, ay);
        }
    }
    float d = dinv[node];
    ushort2 sh = *reinterpret_cast<const ushort2*>(&HH[rb]);
    float hx = fmaf(ax, d, bf2f(sh.x));
    float hy = fmaf(ay, d, bf2f(sh.y));
    *reinterpret_cast<ushort2*>(&OH[rb]) = make_ushort2(f2bf(hx), f2bf(hy));
}

// ---------------- unified weight prep (1 launch, 512 blocks) ----------------
// blocks 0..127:   W1p = W1@Wp1 row b, transposed to W1pt[256][128] (+zero stats)
// blocks 128..383: W0 [512][128] -> W0t [128][512]
// blocks 384..511: Wp2 [256][128] -> Wp2t [128][256]
__global__ void k_wprep(const float* __restrict__ W0, const float* __restrict__ W1,
                        const float* __restrict__ Wp1, const float* __restrict__ Wp2,
                        unsigned short* __restrict__ W0t, unsigned short* __restrict__ W1pt,
                        unsigned short* __restrict__ Wp2t, float* __restrict__ stats) {
    int b = blockIdx.x, t = threadIdx.x;
    if (b < 128) {
        if (b < 2) stats[b * 256 + t] = 0.f;
        float s = 0.f;
        for (int k = 0; k < 128; ++k) s = fmaf(W1[b * 128 + k], Wp1[k * 256 + t], s);
        W1pt[t * 128 + b] = f2bf(s);
    } else if (b < 384) {
        int idx = (b - 128) * 256 + t;     // W0: K=512, N=128
        int k = idx >> 7, n = idx & 127;
        W0t[n * 512 + k] = f2bf(W0[idx]);
    } else {
        int idx = (b - 384) * 256 + t;     // Wp2: K=256, N=128
        int k = idx >> 7, n = idx & 127;
        Wp2t[n * 256 + k] = f2bf(Wp2[idx]);
    }
}

// ---------------- single-bf16 MFMA GEMM (flat layouts) ----------------
// AMODE: 0 = bf16 via global_load_lds; 1 = fp32 reg-staged -> bf16;
//        2 = bf16 reg-staged + BN(scale/shift from LDS-precomputed stats)+ReLU.
// OMODE: 0 = fp32 C (rows<NN); 1 = bf16 all rows (pad incl.).
// STATS: column sum/sumsq over rows < NN.
template <int K, int NCOLS, bool BIAS, int AMODE, int OMODE, bool STATS>
__global__ __launch_bounds__(512) void k_mfma(
    const unsigned short* __restrict__ AH, const float* __restrict__ Af,
    const unsigned short* __restrict__ BH, const float* __restrict__ bias,
    const float* __restrict__ stats, const float* __restrict__ gamma,
    const float* __restrict__ beta,
    float* __restrict__ C, unsigned short* __restrict__ OHs,
    float* __restrict__ statsOut)
{
    __shared__ __align__(16) unsigned short lds[2 * 4096];
    unsigned short* ldsA = lds;
    unsigned short* ldsB = lds + 4096;

    const int tid  = threadIdx.x;
    const int lane = tid & 63;
    const int wid  = tid >> 6;
    const int wm   = wid >> 1;
    const int wn   = wid & 1;
    const int row0 = blockIdx.x * 128;
    const int col0 = blockIdx.y * 128;

    const int srow  = tid >> 2;
    const int skg   = tid & 3;
    const int skswz = skg ^ ((srow >> 1) & 3);  // inverse swizzle on SOURCE
    const size_t aSrc = (size_t)(row0 + srow) * K + skswz * 8;
    const size_t bSrc = (size_t)(col0 + srow) * K + skswz * 8;

    const int frow = lane & 15;
    const int fkg  = lane >> 4;

    __shared__ float s_scl[256], s_shf[256];
    if constexpr (AMODE == 2) {
        if (tid < K) {
            float mu  = stats[tid] * (1.0f / NN);
            float var = stats[256 + tid] * (1.0f / NN) - mu * mu;
            float s = gamma[tid] * rsqrtf(var + 1e-5f);
            s_scl[tid] = s;
            s_shf[tid] = beta[tid] - mu * s;
        }
        __syncthreads();
    }

    f32x4 acc[2][4] = {};

    for (int k0 = 0; k0 < K; k0 += 32) {
        if constexpr (AMODE == 1) {
            float4 f0, f1;
            if (row0 + srow < NN) {
                const float* ap = Af + aSrc + k0;
                f0 = *reinterpret_cast<const float4*>(ap);
                f1 = *reinterpret_cast<const float4*>(ap + 4);
            } else {
                f0 = make_float4(0.f, 0.f, 0.f, 0.f);
                f1 = f0;
            }
            uint4 w;
            w.x = (unsigned)f2bf(f0.x) | ((unsigned)f2bf(f0.y) << 16);
            w.y = (unsigned)f2bf(f0.z) | ((unsigned)f2bf(f0.w) << 16);
            w.z = (unsigned)f2bf(f1.x) | ((unsigned)f2bf(f1.y) << 16);
            w.w = (unsigned)f2bf(f1.z) | ((unsigned)f2bf(f1.w) << 16);
            *reinterpret_cast<uint4*>(&ldsA[tid * 8]) = w;
        } else if constexpr (AMODE == 2) {
            uint4 raw = *reinterpret_cast<const uint4*>(&AH[aSrc + k0]);
            unsigned rw[4] = {raw.x, raw.y, raw.z, raw.w};
            int kc = k0 + skswz * 8;
            float vv[8];
#pragma unroll
            for (int q = 0; q < 8; ++q) {
                float z = bf2f((unsigned short)((q & 1) ? (rw[q >> 1] >> 16)
                                                        : (rw[q >> 1] & 0xFFFF)));
                vv[q] = fmaxf(fmaf(z, s_scl[kc + q], s_shf[kc + q]), 0.f);
            }
            uint4 w;
            w.x = (unsigned)f2bf(vv[0]) | ((unsigned)f2bf(vv[1]) << 16);
            w.y = (unsigned)f2bf(vv[2]) | ((unsigned)f2bf(vv[3]) << 16);
            w.z = (unsigned)f2bf(vv[4]) | ((unsigned)f2bf(vv[5]) << 16);
            w.w = (unsigned)f2bf(vv[6]) | ((unsigned)f2bf(vv[7]) << 16);
            *reinterpret_cast<uint4*>(&ldsA[tid * 8]) = w;
        } else {
            gload16(AH + aSrc + k0, ldsA + tid * 8);
        }
        gload16(BH + bSrc + k0, ldsB + tid * 8);
        __syncthreads();

        bf16x8 a_h[2], b_h[4];
#pragma unroll
        for (int mi = 0; mi < 2; ++mi) {
            int ar  = wm * 32 + mi * 16 + frow;
            int idx = ar * 32 + ((fkg ^ ((ar >> 1) & 3)) * 8);
            a_h[mi] = *reinterpret_cast<const bf16x8*>(&ldsA[idx]);
        }
#pragma unroll
        for (int ni = 0; ni < 4; ++ni) {
            int bc  = wn * 64 + ni * 16 + frow;
            int idx = bc * 32 + ((fkg ^ ((bc >> 1) & 3)) * 8);
            b_h[ni] = *reinterpret_cast<const bf16x8*>(&ldsB[idx]);
        }
#pragma unroll
        for (int mi = 0; mi < 2; ++mi)
#pragma unroll
            for (int ni = 0; ni < 4; ++ni)
                acc[mi][ni] = __builtin_amdgcn_mfma_f32_16x16x32_bf16(a_h[mi], b_h[ni], acc[mi][ni], 0, 0, 0);
        __syncthreads();
    }

    float psum[4] = {0.f, 0.f, 0.f, 0.f}, psq[4] = {0.f, 0.f, 0.f, 0.f};
#pragma unroll
    for (int mi = 0; mi < 2; ++mi) {
        int rbase = row0 + wm * 32 + mi * 16 + (lane >> 4) * 4;
#pragma unroll
        for (int ni = 0; ni < 4; ++ni) {
            int col = col0 + wn * 64 + ni * 16 + (lane & 15);
            float b = BIAS ? bias[col] : 0.f;
#pragma unroll
            for (int r = 0; r < 4; ++r) {
                int row = rbase + r;
                float v = acc[mi][ni][r] + b;
                if constexpr (STATS) {
                    if (row < NN) { psum[ni] += v; psq[ni] = fmaf(v, v, psq[ni]); }
                }
                if constexpr (OMODE == 1) {
                    OHs[(size_t)row * NCOLS + col] = f2bf(v);   // pad rows too
                } else {
                    if (row < NN) C[(size_t)row * NCOLS + col] = v;
                }
            }
        }
    }

    if constexpr (STATS) {
        __shared__ float s_sum[128], s_sq[128];
        if (tid < 128) { s_sum[tid] = 0.f; s_sq[tid] = 0.f; }
        __syncthreads();
#pragma unroll
        for (int ni = 0; ni < 4; ++ni) {
            float a = psum[ni], q = psq[ni];
            a += __shfl_xor(a, 16); a += __shfl_xor(a, 32);
            q += __shfl_xor(q, 16); q += __shfl_xor(q, 32);
            if ((lane >> 4) == 0) {
                int cl = wn * 64 + ni * 16 + lane;   // lane < 16 here
                atomicAdd(&s_sum[cl], a);
                atomicAdd(&s_sq[cl], q);
            }
        }
        __syncthreads();
        if (tid < 128) {
            atomicAdd(&statsOut[col0 + tid], s_sum[tid]);
            atomicAdd(&statsOut[256 + col0 + tid], s_sq[tid]);
        }
    }
}

extern "C" void kernel_launch(void* const* d_in, const int* in_sizes, int n_in,
                              void* d_out, int out_size, void* d_ws, size_t ws_size,
                              hipStream_t stream) {
    const float* feat  = (const float*)d_in[0];
    const int*   src   = (const int*)d_in[1];
    const int*   dst   = (const int*)d_in[2];
    const float* W0    = (const float*)d_in[3];
    const float* W1    = (const float*)d_in[4];
    const float* Wp1   = (const float*)d_in[5];
    const float* bp1   = (const float*)d_in[6];
    const float* gamma = (const float*)d_in[7];
    const float* beta  = (const float*)d_in[8];
    const float* Wp2   = (const float*)d_in[9];
    const float* bp2   = (const float*)d_in[10];
    float* out = (float*)d_out;

    char* wsb = (char*)d_ws;
    float* dinv   = (float*)(wsb + 4ull * 0);
    int*   cnt    = (int*)  (wsb + 4ull * 50048);     // cnt+cursor adjacent: 1 memset
    int*   cursor = (int*)  (wsb + 4ull * 100096);
    int*   rowoff = (int*)  (wsb + 4ull * 150144);
    int*   bsum   = (int*)  (wsb + 4ull * 200192);
    int*   boff   = (int*)  (wsb + 4ull * 200448);
    int*   eidx   = (int*)  (wsb + 4ull * 200704);
    float* stats  = (float*)(wsb + 4ull * 1000704);
    unsigned short* W0t  = (unsigned short*)(wsb + 4ull * 1034496);   // 65536 u16
    unsigned short* W1pt = W0t + 65536;                               // 32768 u16
    unsigned short* Wp2t = W1pt + 32768;                              // 32768 u16
    // flat H buffers: [NNP][128] u16 each (3203072 words apiece)
    unsigned short* H0 = (unsigned short*)(wsb + 4ull * 1165568);
    unsigned short* h1 = (unsigned short*)(wsb + 4ull * 4368640);
    unsigned short* h2 = H0;   // reuse after H0 consumed
    unsigned short* ZH = (unsigned short*)(wsb + 4ull * 7571712);     // [NNP][256] u16

    const int GX = NNP / 128;  // 391

    // ---- CSR build ----
    hipMemsetAsync(cnt, 0, 2 * 50048 * sizeof(int), stream);   // cnt + cursor
    k_count<<<(NE + 255) / 256, 256, 0, stream>>>(dst, cnt);
    k_bsum<<<NB, 256, 0, stream>>>(cnt, bsum);
    k_scan_bsum<<<1, 256, 0, stream>>>(bsum, boff);
    k_scan_block<<<NB, 256, 0, stream>>>(cnt, boff, rowoff, dinv);
    k_fill<<<(NE + 255) / 256, 256, 0, stream>>>(src, dst, rowoff, cursor, eidx);

    // ---- weight prep (1 launch; also zeroes stats) ----
    k_wprep<<<512, 256, 0, stream>>>(W0, W1, Wp1, Wp2, W0t, W1pt, Wp2t, stats);

    // H0 = feat @ W0  (A fp32 reg-staged -> bf16, single pass, bf16 out)
    k_mfma<512, 128, false, 1, 1, false><<<dim3(GX, 1), 512, 0, stream>>>(
        nullptr, feat, W0t, nullptr, nullptr, nullptr, nullptr,
        nullptr, H0, nullptr);

    // h1 = conv(H0); h2 = conv(h1)   [conv commutes with right-mult by W]
    k_gather_shfl<<<NNP / 4, 256, 0, stream>>>(H0, dinv, rowoff, cnt, eidx, h1);
    k_gather_shfl<<<NNP / 4, 256, 0, stream>>>(h1, dinv, rowoff, cnt, eidx, h2);

    // Z = h2 @ (W1@Wp1) + bp1  [NNP,256] bf16, fused BN column stats
    k_mfma<128, 256, true, 0, 1, true><<<dim3(GX, 2), 512, 0, stream>>>(
        h2, nullptr, W1pt, bp1, nullptr, nullptr, nullptr,
        nullptr, ZH, stats);

    // out = relu(BN(Z)) @ Wp2 + bp2  (BN scale/shift precomputed per block in LDS)
    k_mfma<256, 128, true, 2, 0, false><<<dim3(GX, 1), 512, 0, stream>>>(
        ZH, nullptr, Wp2t, bp2, stats, gamma, beta,
        out, nullptr, nullptr);
}

// Round 10
// 215.781 us; speedup vs baseline: 1.9367x; 1.1015x over previous
//
#include <hip/hip_runtime.h>
#include <math.h>

constexpr int NN  = 50000;
constexpr int NE  = 800000;
constexpr int NNP = 50048;             // padded rows = 391 * 128
constexpr int NB  = (NN + 255) / 256;  // scan blocks
constexpr int GX  = NNP / 128;         // 391 GEMM row tiles
constexpr int FILLB = (NE + 511) / 512;

typedef __bf16 bf16x8 __attribute__((ext_vector_type(8)));
typedef float  f32x4  __attribute__((ext_vector_type(4)));
typedef __attribute__((address_space(1))) unsigned int as1_uint;
typedef __attribute__((address_space(3))) unsigned int as3_uint;

__device__ __forceinline__ unsigned short f2bf(float x) {  // RNE fp32->bf16 bits
    unsigned int u = __float_as_uint(x);
    return (unsigned short)((u + 0x7FFFu + ((u >> 16) & 1u)) >> 16);
}
__device__ __forceinline__ float bf2f(unsigned short h) {
    return __uint_as_float(((unsigned int)h) << 16);
}
__device__ __forceinline__ float rdlanef(float v, int j) {
    return __uint_as_float(__builtin_amdgcn_readlane(__float_as_uint(v), j));
}

__device__ __forceinline__ void gload16(const unsigned short* g, unsigned short* l) {
    __builtin_amdgcn_global_load_lds((const as1_uint*)(unsigned long long)g,
                                     (as3_uint*)(unsigned long long)l, 16, 0, 0);
}

// ---------------- CSR build ----------------
__global__ void k_bsum(const int* __restrict__ cnt, int* __restrict__ bsum) {
    int i = blockIdx.x * 256 + threadIdx.x;
    int v = (i < NN) ? cnt[i] : 0;
#pragma unroll
    for (int off = 32; off; off >>= 1) v += __shfl_down(v, off, 64);
    __shared__ int tmp[4];
    if ((threadIdx.x & 63) == 0) tmp[threadIdx.x >> 6] = v;
    __syncthreads();
    if (threadIdx.x == 0) bsum[blockIdx.x] = tmp[0] + tmp[1] + tmp[2] + tmp[3];
}

__global__ void k_scan_bsum(const int* __restrict__ bsum, int* __restrict__ boff) {
    __shared__ int s[256];
    int t = threadIdx.x;
    int v = (t < NB) ? bsum[t] : 0;
    s[t] = v;
    __syncthreads();
    for (int off = 1; off < 256; off <<= 1) {
        int u = (t >= off) ? s[t - off] : 0;
        __syncthreads();
        s[t] += u;
        __syncthreads();
    }
    if (t < NB) boff[t] = s[t] - v;
}

// also emits dinv (folded k_dinv)
__global__ void k_scan_block(const int* __restrict__ cnt, const int* __restrict__ boff,
                             int* __restrict__ rowoff, float* __restrict__ dinv) {
    __shared__ int s[256];
    int t = threadIdx.x;
    int i = blockIdx.x * 256 + t;
    int v = (i < NN) ? cnt[i] : 0;
    s[t] = v;
    __syncthreads();
    for (int off = 1; off < 256; off <<= 1) {
        int u = (t >= off) ? s[t - off] : 0;
        __syncthreads();
        s[t] += u;
        __syncthreads();
    }
    if (i < NN) {
        rowoff[i] = boff[blockIdx.x] + s[t] - v;
        dinv[i] = rsqrtf(fmaxf((float)v, 1.0f));
    }
}

// ---------------- shfl-broadcast low_conv gather (single bf16) ----------------
__global__ __launch_bounds__(256) void k_gather_shfl(
    const unsigned short* __restrict__ HH, const float* __restrict__ dinv,
    const int* __restrict__ rowoff, const int* __restrict__ cnt,
    const int* __restrict__ eidx, unsigned short* __restrict__ OH)
{
    int node = blockIdx.x * 4 + (threadIdx.x >> 6);
    int lane = threadIdx.x & 63;
    if (node >= NNP) return;
    size_t rb = (size_t)node * 128 + lane * 2;
    if (node >= NN) {  // zero pad rows
        *reinterpret_cast<ushort2*>(&OH[rb]) = make_ushort2(0, 0);
        return;
    }
    int beg = rowoff[node], n = cnt[node];
    int c2 = lane * 2;
    float ax = 0.f, ay = 0.f;
    for (int jj = 0; jj < n; jj += 64) {
        int m = min(n - jj, 64);
        int el = (lane < m) ? eidx[beg + jj + lane] : 0;
        float dl = dinv[el];
        int j = 0;
        for (; j + 8 <= m; j += 8) {   // 8 independent row loads in flight
            int s0 = __builtin_amdgcn_readlane(el, j);
            int s1 = __builtin_amdgcn_readlane(el, j + 1);
            int s2 = __builtin_amdgcn_readlane(el, j + 2);
            int s3 = __builtin_amdgcn_readlane(el, j + 3);
            int s4 = __builtin_amdgcn_readlane(el, j + 4);
            int s5 = __builtin_amdgcn_readlane(el, j + 5);
            int s6 = __builtin_amdgcn_readlane(el, j + 6);
            int s7 = __builtin_amdgcn_readlane(el, j + 7);
            ushort2 v0 = *reinterpret_cast<const ushort2*>(&HH[(size_t)s0 * 128 + c2]);
            ushort2 v1 = *reinterpret_cast<const ushort2*>(&HH[(size_t)s1 * 128 + c2]);
            ushort2 v2 = *reinterpret_cast<const ushort2*>(&HH[(size_t)s2 * 128 + c2]);
            ushort2 v3 = *reinterpret_cast<const ushort2*>(&HH[(size_t)s3 * 128 + c2]);
            ushort2 v4 = *reinterpret_cast<const ushort2*>(&HH[(size_t)s4 * 128 + c2]);
            ushort2 v5 = *reinterpret_cast<const ushort2*>(&HH[(size_t)s5 * 128 + c2]);
            ushort2 v6 = *reinterpret_cast<const ushort2*>(&HH[(size_t)s6 * 128 + c2]);
            ushort2 v7 = *reinterpret_cast<const ushort2*>(&HH[(size_t)s7 * 128 + c2]);
            float d0 = rdlanef(dl, j),     d1 = rdlanef(dl, j + 1);
            float d2 = rdlanef(dl, j + 2), d3 = rdlanef(dl, j + 3);
            float d4 = rdlanef(dl, j + 4), d5 = rdlanef(dl, j + 5);
            float d6 = rdlanef(dl, j + 6), d7 = rdlanef(dl, j + 7);
            ax = fmaf(bf2f(v0.x), d0, ax); ay = fmaf(bf2f(v0.y), d0, ay);
            ax = fmaf(bf2f(v1.x), d1, ax); ay = fmaf(bf2f(v1.y), d1, ay);
            ax = fmaf(bf2f(v2.x), d2, ax); ay = fmaf(bf2f(v2.y), d2, ay);
            ax = fmaf(bf2f(v3.x), d3, ax); ay = fmaf(bf2f(v3.y), d3, ay);
            ax = fmaf(bf2f(v4.x), d4, ax); ay = fmaf(bf2f(v4.y), d4, ay);
            ax = fmaf(bf2f(v5.x), d5, ax); ay = fmaf(bf2f(v5.y), d5, ay);
            ax = fmaf(bf2f(v6.x), d6, ax); ay = fmaf(bf2f(v6.y), d6, ay);
            ax = fmaf(bf2f(v7.x), d7, ax); ay = fmaf(bf2f(v7.y), d7, ay);
        }
        for (; j < m; ++j) {
            int s0 = __builtin_amdgcn_readlane(el, j);
            float d0 = rdlanef(dl, j);
            ushort2 v0 = *reinterpret_cast<const ushort2*>(&HH[(size_t)s0 * 128 + c2]);
            ax = fmaf(bf2f(v0.x), d0, ax); ay = fmaf(bf2f(v0.y), d0, ay);
        }
    }
    float d = dinv[node];
    ushort2 sh = *reinterpret_cast<const ushort2*>(&HH[rb]);
    float hx = fmaf(ax, d, bf2f(sh.x));
    float hy = fmaf(ay, d, bf2f(sh.y));
    *reinterpret_cast<ushort2*>(&OH[rb]) = make_ushort2(f2bf(hx), f2bf(hy));
}

// ---------------- unified weight prep + dst histogram (1 launch) ----------------
// blocks 0..127:   W1p = W1@Wp1 row b -> W1pt[256][128] (+zero stats)
// blocks 128..383: W0 -> W0t;  blocks 384..511: Wp2 -> Wp2t
// blocks 512.. :   k_count (dst histogram)
__global__ void k_wprep_count(const float* __restrict__ W0, const float* __restrict__ W1,
                              const float* __restrict__ Wp1, const float* __restrict__ Wp2,
                              unsigned short* __restrict__ W0t, unsigned short* __restrict__ W1pt,
                              unsigned short* __restrict__ Wp2t, float* __restrict__ stats,
                              const int* __restrict__ dst, int* __restrict__ cnt) {
    int b = blockIdx.x, t = threadIdx.x;
    if (b >= 512) {
        int i = (b - 512) * 256 + t;
        if (i < NE) atomicAdd(&cnt[dst[i]], 1);
        return;
    }
    if (b < 128) {
        if (b < 2) stats[b * 256 + t] = 0.f;
        float s = 0.f;
        for (int k = 0; k < 128; ++k) s = fmaf(W1[b * 128 + k], Wp1[k * 256 + t], s);
        W1pt[t * 128 + b] = f2bf(s);
    } else if (b < 384) {
        int idx = (b - 128) * 256 + t;     // W0: K=512, N=128
        int k = idx >> 7, n = idx & 127;
        W0t[n * 512 + k] = f2bf(W0[idx]);
    } else {
        int idx = (b - 384) * 256 + t;     // Wp2: K=256, N=128
        int k = idx >> 7, n = idx & 127;
        Wp2t[n * 256 + k] = f2bf(Wp2[idx]);
    }
}

// ---------------- fused GEMM1 (feat@W0 -> bf16) + CSR fill ----------------
// blocks 0..GX-1: 128x128 MFMA GEMM, K=512, A fp32 reg-staged.
// blocks GX.. : eidx fill (latency-bound, hides under GEMM compute).
__global__ __launch_bounds__(512) void k_gemm1_fill(
    const float* __restrict__ Af, const unsigned short* __restrict__ BH,
    unsigned short* __restrict__ OHs,
    const int* __restrict__ src, const int* __restrict__ dst,
    const int* __restrict__ rowoff, int* __restrict__ cursor, int* __restrict__ eidx)
{
    if (blockIdx.x >= GX) {   // ---- fill path ----
        int e = (blockIdx.x - GX) * 512 + threadIdx.x;
        if (e < NE) {
            int d = dst[e];
            int p = atomicAdd(&cursor[d], 1);
            eidx[rowoff[d] + p] = src[e];
        }
        return;
    }
    // ---- GEMM path (K=512, NCOLS=128) ----
    constexpr int K = 512, NCOLS = 128;
    __shared__ __align__(16) unsigned short lds[2 * 4096];
    unsigned short* ldsA = lds;
    unsigned short* ldsB = lds + 4096;

    const int tid  = threadIdx.x;
    const int lane = tid & 63;
    const int wid  = tid >> 6;
    const int wm   = wid >> 1;
    const int wn   = wid & 1;
    const int row0 = blockIdx.x * 128;

    const int srow  = tid >> 2;
    const int skg   = tid & 3;
    const int skswz = skg ^ ((srow >> 1) & 3);
    const size_t aSrc = (size_t)(row0 + srow) * K + skswz * 8;
    const size_t bSrc = (size_t)srow * K + skswz * 8;

    const int frow = lane & 15;
    const int fkg  = lane >> 4;

    f32x4 acc[2][4] = {};

    for (int k0 = 0; k0 < K; k0 += 32) {
        float4 f0, f1;
        if (row0 + srow < NN) {
            const float* ap = Af + aSrc + k0;
            f0 = *reinterpret_cast<const float4*>(ap);
            f1 = *reinterpret_cast<const float4*>(ap + 4);
        } else {
            f0 = make_float4(0.f, 0.f, 0.f, 0.f);
            f1 = f0;
        }
        uint4 w;
        w.x = (unsigned)f2bf(f0.x) | ((unsigned)f2bf(f0.y) << 16);
        w.y = (unsigned)f2bf(f0.z) | ((unsigned)f2bf(f0.w) << 16);
        w.z = (unsigned)f2bf(f1.x) | ((unsigned)f2bf(f1.y) << 16);
        w.w = (unsigned)f2bf(f1.z) | ((unsigned)f2bf(f1.w) << 16);
        *reinterpret_cast<uint4*>(&ldsA[tid * 8]) = w;
        gload16(BH + bSrc + k0, ldsB + tid * 8);
        __syncthreads();

        bf16x8 a_h[2], b_h[4];
#pragma unroll
        for (int mi = 0; mi < 2; ++mi) {
            int ar  = wm * 32 + mi * 16 + frow;
            int idx = ar * 32 + ((fkg ^ ((ar >> 1) & 3)) * 8);
            a_h[mi] = *reinterpret_cast<const bf16x8*>(&ldsA[idx]);
        }
#pragma unroll
        for (int ni = 0; ni < 4; ++ni) {
            int bc  = wn * 64 + ni * 16 + frow;
            int idx = bc * 32 + ((fkg ^ ((bc >> 1) & 3)) * 8);
            b_h[ni] = *reinterpret_cast<const bf16x8*>(&ldsB[idx]);
        }
#pragma unroll
        for (int mi = 0; mi < 2; ++mi)
#pragma unroll
            for (int ni = 0; ni < 4; ++ni)
                acc[mi][ni] = __builtin_amdgcn_mfma_f32_16x16x32_bf16(a_h[mi], b_h[ni], acc[mi][ni], 0, 0, 0);
        __syncthreads();
    }

#pragma unroll
    for (int mi = 0; mi < 2; ++mi) {
        int rbase = row0 + wm * 32 + mi * 16 + (lane >> 4) * 4;
#pragma unroll
        for (int ni = 0; ni < 4; ++ni) {
            int col = wn * 64 + ni * 16 + (lane & 15);
#pragma unroll
            for (int r = 0; r < 4; ++r)
                OHs[(size_t)(rbase + r) * NCOLS + col] = f2bf(acc[mi][ni][r]);
        }
    }
}

// ---------------- single-bf16 MFMA GEMM (flat layouts) ----------------
// AMODE: 0 = bf16 via global_load_lds; 2 = bf16 reg-staged + BN+ReLU (LDS-precomputed).
// OMODE: 0 = fp32 C (rows<NN); 1 = bf16 all rows. STATS: column sum/sumsq (rows<NN).
template <int K, int NCOLS, bool BIAS, int AMODE, int OMODE, bool STATS>
__global__ __launch_bounds__(512) void k_mfma(
    const unsigned short* __restrict__ AH, const unsigned short* __restrict__ BH,
    const float* __restrict__ bias,
    const float* __restrict__ stats, const float* __restrict__ gamma,
    const float* __restrict__ beta,
    float* __restrict__ C, unsigned short* __restrict__ OHs,
    float* __restrict__ statsOut)
{
    __shared__ __align__(16) unsigned short lds[2 * 4096];
    unsigned short* ldsA = lds;
    unsigned short* ldsB = lds + 4096;

    const int tid  = threadIdx.x;
    const int lane = tid & 63;
    const int wid  = tid >> 6;
    const int wm   = wid >> 1;
    const int wn   = wid & 1;
    const int row0 = blockIdx.x * 128;
    const int col0 = blockIdx.y * 128;

    const int srow  = tid >> 2;
    const int skg   = tid & 3;
    const int skswz = skg ^ ((srow >> 1) & 3);
    const size_t aSrc = (size_t)(row0 + srow) * K + skswz * 8;
    const size_t bSrc = (size_t)(col0 + srow) * K + skswz * 8;

    const int frow = lane & 15;
    const int fkg  = lane >> 4;

    __shared__ float s_scl[256], s_shf[256];
    if constexpr (AMODE == 2) {
        if (tid < K) {
            float mu  = stats[tid] * (1.0f / NN);
            float var = stats[256 + tid] * (1.0f / NN) - mu * mu;
            float s = gamma[tid] * rsqrtf(var + 1e-5f);
            s_scl[tid] = s;
            s_shf[tid] = beta[tid] - mu * s;
        }
        __syncthreads();
    }

    f32x4 acc[2][4] = {};

    for (int k0 = 0; k0 < K; k0 += 32) {
        if constexpr (AMODE == 2) {
            uint4 raw = *reinterpret_cast<const uint4*>(&AH[aSrc + k0]);
            unsigned rw[4] = {raw.x, raw.y, raw.z, raw.w};
            int kc = k0 + skswz * 8;
            float vv[8];
#pragma unroll
            for (int q = 0; q < 8; ++q) {
                float z = bf2f((unsigned short)((q & 1) ? (rw[q >> 1] >> 16)
                                                        : (rw[q >> 1] & 0xFFFF)));
                vv[q] = fmaxf(fmaf(z, s_scl[kc + q], s_shf[kc + q]), 0.f);
            }
            uint4 w;
            w.x = (unsigned)f2bf(vv[0]) | ((unsigned)f2bf(vv[1]) << 16);
            w.y = (unsigned)f2bf(vv[2]) | ((unsigned)f2bf(vv[3]) << 16);
            w.z = (unsigned)f2bf(vv[4]) | ((unsigned)f2bf(vv[5]) << 16);
            w.w = (unsigned)f2bf(vv[6]) | ((unsigned)f2bf(vv[7]) << 16);
            *reinterpret_cast<uint4*>(&ldsA[tid * 8]) = w;
        } else {
            gload16(AH + aSrc + k0, ldsA + tid * 8);
        }
        gload16(BH + bSrc + k0, ldsB + tid * 8);
        __syncthreads();

        bf16x8 a_h[2], b_h[4];
#pragma unroll
        for (int mi = 0; mi < 2; ++mi) {
            int ar  = wm * 32 + mi * 16 + frow;
            int idx = ar * 32 + ((fkg ^ ((ar >> 1) & 3)) * 8);
            a_h[mi] = *reinterpret_cast<const bf16x8*>(&ldsA[idx]);
        }
#pragma unroll
        for (int ni = 0; ni < 4; ++ni) {
            int bc  = wn * 64 + ni * 16 + frow;
            int idx = bc * 32 + ((fkg ^ ((bc >> 1) & 3)) * 8);
            b_h[ni] = *reinterpret_cast<const bf16x8*>(&ldsB[idx]);
        }
#pragma unroll
        for (int mi = 0; mi < 2; ++mi)
#pragma unroll
            for (int ni = 0; ni < 4; ++ni)
                acc[mi][ni] = __builtin_amdgcn_mfma_f32_16x16x32_bf16(a_h[mi], b_h[ni], acc[mi][ni], 0, 0, 0);
        __syncthreads();
    }

    float psum[4] = {0.f, 0.f, 0.f, 0.f}, psq[4] = {0.f, 0.f, 0.f, 0.f};
#pragma unroll
    for (int mi = 0; mi < 2; ++mi) {
        int rbase = row0 + wm * 32 + mi * 16 + (lane >> 4) * 4;
#pragma unroll
        for (int ni = 0; ni < 4; ++ni) {
            int col = col0 + wn * 64 + ni * 16 + (lane & 15);
            float b = BIAS ? bias[col] : 0.f;
#pragma unroll
            for (int r = 0; r < 4; ++r) {
                int row = rbase + r;
                float v = acc[mi][ni][r] + b;
                if constexpr (STATS) {
                    if (row < NN) { psum[ni] += v; psq[ni] = fmaf(v, v, psq[ni]); }
                }
                if constexpr (OMODE == 1) {
                    OHs[(size_t)row * NCOLS + col] = f2bf(v);   // pad rows too
                } else {
                    if (row < NN) C[(size_t)row * NCOLS + col] = v;
                }
            }
        }
    }

    if constexpr (STATS) {
        __shared__ float s_sum[128], s_sq[128];
        if (tid < 128) { s_sum[tid] = 0.f; s_sq[tid] = 0.f; }
        __syncthreads();
#pragma unroll
        for (int ni = 0; ni < 4; ++ni) {
            float a = psum[ni], q = psq[ni];
            a += __shfl_xor(a, 16); a += __shfl_xor(a, 32);
            q += __shfl_xor(q, 16); q += __shfl_xor(q, 32);
            if ((lane >> 4) == 0) {
                int cl = wn * 64 + ni * 16 + lane;
                atomicAdd(&s_sum[cl], a);
                atomicAdd(&s_sq[cl], q);
            }
        }
        __syncthreads();
        if (tid < 128) {
            atomicAdd(&statsOut[col0 + tid], s_sum[tid]);
            atomicAdd(&statsOut[256 + col0 + tid], s_sq[tid]);
        }
    }
}

extern "C" void kernel_launch(void* const* d_in, const int* in_sizes, int n_in,
                              void* d_out, int out_size, void* d_ws, size_t ws_size,
                              hipStream_t stream) {
    const float* feat  = (const float*)d_in[0];
    const int*   src   = (const int*)d_in[1];
    const int*   dst   = (const int*)d_in[2];
    const float* W0    = (const float*)d_in[3];
    const float* W1    = (const float*)d_in[4];
    const float* Wp1   = (const float*)d_in[5];
    const float* bp1   = (const float*)d_in[6];
    const float* gamma = (const float*)d_in[7];
    const float* beta  = (const float*)d_in[8];
    const float* Wp2   = (const float*)d_in[9];
    const float* bp2   = (const float*)d_in[10];
    float* out = (float*)d_out;

    char* wsb = (char*)d_ws;
    float* dinv   = (float*)(wsb + 4ull * 0);
    int*   cnt    = (int*)  (wsb + 4ull * 50048);     // cnt+cursor adjacent: 1 memset
    int*   cursor = (int*)  (wsb + 4ull * 100096);
    int*   rowoff = (int*)  (wsb + 4ull * 150144);
    int*   bsum   = (int*)  (wsb + 4ull * 200192);
    int*   boff   = (int*)  (wsb + 4ull * 200448);
    int*   eidx   = (int*)  (wsb + 4ull * 200704);
    float* stats  = (float*)(wsb + 4ull * 1000704);
    unsigned short* W0t  = (unsigned short*)(wsb + 4ull * 1034496);   // 65536 u16
    unsigned short* W1pt = W0t + 65536;                               // 32768 u16
    unsigned short* Wp2t = W1pt + 32768;                              // 32768 u16
    unsigned short* H0 = (unsigned short*)(wsb + 4ull * 1165568);     // [NNP][128] u16
    unsigned short* h1 = (unsigned short*)(wsb + 4ull * 4368640);
    unsigned short* h2 = H0;   // reuse after H0 consumed
    unsigned short* ZH = (unsigned short*)(wsb + 4ull * 7571712);     // [NNP][256] u16

    // ---- CSR build (count fused into wprep) ----
    hipMemsetAsync(cnt, 0, 2 * 50048 * sizeof(int), stream);   // cnt + cursor
    k_wprep_count<<<512 + (NE + 255) / 256, 256, 0, stream>>>(
        W0, W1, Wp1, Wp2, W0t, W1pt, Wp2t, stats, dst, cnt);
    k_bsum<<<NB, 256, 0, stream>>>(cnt, bsum);
    k_scan_bsum<<<1, 256, 0, stream>>>(bsum, boff);
    k_scan_block<<<NB, 256, 0, stream>>>(cnt, boff, rowoff, dinv);

    // H0 = feat @ W0 (bf16 out) FUSED with CSR eidx fill
    k_gemm1_fill<<<GX + FILLB, 512, 0, stream>>>(
        feat, W0t, H0, src, dst, rowoff, cursor, eidx);

    // h1 = conv(H0); h2 = conv(h1)   [conv commutes with right-mult by W]
    k_gather_shfl<<<NNP / 4, 256, 0, stream>>>(H0, dinv, rowoff, cnt, eidx, h1);
    k_gather_shfl<<<NNP / 4, 256, 0, stream>>>(h1, dinv, rowoff, cnt, eidx, h2);

    // Z = h2 @ (W1@Wp1) + bp1  [NNP,256] bf16, fused BN column stats
    k_mfma<128, 256, true, 0, 1, true><<<dim3(GX, 2), 512, 0, stream>>>(
        h2, W1pt, bp1, nullptr, nullptr, nullptr, nullptr, ZH, stats);

    // out = relu(BN(Z)) @ Wp2 + bp2  (BN scale/shift precomputed per block in LDS)
    k_mfma<256, 128, true, 2, 0, false><<<dim3(GX, 1), 512, 0, stream>>>(
        ZH, Wp2t, bp2, stats, gamma, beta, out, nullptr, nullptr);
}

// Round 11
// 196.785 us; speedup vs baseline: 2.1237x; 1.0965x over previous
//
#include <hip/hip_runtime.h>
#include <math.h>

constexpr int NN  = 50000;
constexpr int NE  = 800000;
constexpr int NNP = 50048;             // padded rows = 391 * 128
constexpr int NB  = (NN + 255) / 256;  // scan blocks
constexpr int GX  = NNP / 128;         // 391 GEMM row tiles
constexpr int FILLB = (NE + 511) / 512;

typedef __bf16 bf16x8 __attribute__((ext_vector_type(8)));
typedef float  f32x4  __attribute__((ext_vector_type(4)));
typedef __attribute__((address_space(1))) unsigned int as1_uint;
typedef __attribute__((address_space(3))) unsigned int as3_uint;

__device__ __forceinline__ unsigned short f2bf(float x) {  // RNE fp32->bf16 bits
    unsigned int u = __float_as_uint(x);
    return (unsigned short)((u + 0x7FFFu + ((u >> 16) & 1u)) >> 16);
}
__device__ __forceinline__ float bf2f(unsigned short h) {
    return __uint_as_float(((unsigned int)h) << 16);
}
__device__ __forceinline__ float rdlanef(float v, int j) {
    return __uint_as_float(__builtin_amdgcn_readlane(__float_as_uint(v), j));
}

__device__ __forceinline__ void gload16(const unsigned short* g, unsigned short* l) {
    __builtin_amdgcn_global_load_lds((const as1_uint*)(unsigned long long)g,
                                     (as3_uint*)(unsigned long long)l, 16, 0, 0);
}

// ---------------- CSR build ----------------
__global__ void k_bsum(const int* __restrict__ cnt, int* __restrict__ bsum) {
    int i = blockIdx.x * 256 + threadIdx.x;
    int v = (i < NN) ? cnt[i] : 0;
#pragma unroll
    for (int off = 32; off; off >>= 1) v += __shfl_down(v, off, 64);
    __shared__ int tmp[4];
    if ((threadIdx.x & 63) == 0) tmp[threadIdx.x >> 6] = v;
    __syncthreads();
    if (threadIdx.x == 0) bsum[blockIdx.x] = tmp[0] + tmp[1] + tmp[2] + tmp[3];
}

__global__ void k_scan_bsum(const int* __restrict__ bsum, int* __restrict__ boff) {
    __shared__ int s[256];
    int t = threadIdx.x;
    int v = (t < NB) ? bsum[t] : 0;
    s[t] = v;
    __syncthreads();
    for (int off = 1; off < 256; off <<= 1) {
        int u = (t >= off) ? s[t - off] : 0;
        __syncthreads();
        s[t] += u;
        __syncthreads();
    }
    if (t < NB) boff[t] = s[t] - v;
}

// also emits dinv (folded k_dinv)
__global__ void k_scan_block(const int* __restrict__ cnt, const int* __restrict__ boff,
                             int* __restrict__ rowoff, float* __restrict__ dinv) {
    __shared__ int s[256];
    int t = threadIdx.x;
    int i = blockIdx.x * 256 + t;
    int v = (i < NN) ? cnt[i] : 0;
    s[t] = v;
    __syncthreads();
    for (int off = 1; off < 256; off <<= 1) {
        int u = (t >= off) ? s[t - off] : 0;
        __syncthreads();
        s[t] += u;
        __syncthreads();
    }
    if (i < NN) {
        rowoff[i] = boff[blockIdx.x] + s[t] - v;
        dinv[i] = rsqrtf(fmaxf((float)v, 1.0f));
    }
}

// ---------------- shfl-broadcast low_conv gather (single bf16) ----------------
// wave = 1 node, 64 lanes x ushort2 = full 256B row per load. eidx+dinv preloaded
// lane-parallel, broadcast via readlane. Predicated groups of 8 (no serial tail):
// pad slots read row 0 with weight 0.
__global__ __launch_bounds__(256) void k_gather_shfl(
    const unsigned short* __restrict__ HH, const float* __restrict__ dinv,
    const int* __restrict__ rowoff, const int* __restrict__ cnt,
    const int* __restrict__ eidx, unsigned short* __restrict__ OH)
{
    int node = blockIdx.x * 4 + (threadIdx.x >> 6);
    int lane = threadIdx.x & 63;
    if (node >= NNP) return;
    size_t rb = (size_t)node * 128 + lane * 2;
    if (node >= NN) {  // zero pad rows
        *reinterpret_cast<ushort2*>(&OH[rb]) = make_ushort2(0, 0);
        return;
    }
    int beg = rowoff[node], n = cnt[node];
    int c2 = lane * 2;
    float ax = 0.f, ay = 0.f;
    for (int jj = 0; jj < n; jj += 64) {
        int m = min(n - jj, 64);
        int el = (lane < m) ? eidx[beg + jj + lane] : 0;   // pad lanes -> node 0
        float dl = dinv[el];
        int mp = (m + 7) & ~7;
        for (int j = 0; j < mp; j += 8) {
            int ss[8]; float dd[8]; ushort2 vv[8];
#pragma unroll
            for (int q = 0; q < 8; ++q) {
                int jq = (j + q) & 63;
                ss[q] = __builtin_amdgcn_readlane(el, jq);
                dd[q] = (j + q < m) ? rdlanef(dl, jq) : 0.f;   // uniform predicate
            }
#pragma unroll
            for (int q = 0; q < 8; ++q)
                vv[q] = *reinterpret_cast<const ushort2*>(&HH[(size_t)ss[q] * 128 + c2]);
#pragma unroll
            for (int q = 0; q < 8; ++q) {
                ax = fmaf(bf2f(vv[q].x), dd[q], ax);
                ay = fmaf(bf2f(vv[q].y), dd[q], ay);
            }
        }
    }
    float d = dinv[node];
    ushort2 sh = *reinterpret_cast<const ushort2*>(&HH[rb]);
    float hx = fmaf(ax, d, bf2f(sh.x));
    float hy = fmaf(ay, d, bf2f(sh.y));
    *reinterpret_cast<ushort2*>(&OH[rb]) = make_ushort2(f2bf(hx), f2bf(hy));
}

// ---------------- unified weight prep + dst histogram + slot assignment ----------------
// blocks 0..127:   W1p = W1@Wp1 row b -> W1pt[256][128] (+zero stats)
// blocks 128..383: W0 -> W0t;  blocks 384..511: Wp2 -> Wp2t
// blocks 512.. :   histogram of dst, recording each edge's slot in pos[e]
__global__ void k_wprep_count(const float* __restrict__ W0, const float* __restrict__ W1,
                              const float* __restrict__ Wp1, const float* __restrict__ Wp2,
                              unsigned short* __restrict__ W0t, unsigned short* __restrict__ W1pt,
                              unsigned short* __restrict__ Wp2t, float* __restrict__ stats,
                              const int* __restrict__ dst, int* __restrict__ cnt,
                              int* __restrict__ pos) {
    int b = blockIdx.x, t = threadIdx.x;
    if (b >= 512) {
        int i = (b - 512) * 256 + t;
        if (i < NE) pos[i] = atomicAdd(&cnt[dst[i]], 1);
        return;
    }
    if (b < 128) {
        if (b < 2) stats[b * 256 + t] = 0.f;
        float s = 0.f;
        for (int k = 0; k < 128; ++k) s = fmaf(W1[b * 128 + k], Wp1[k * 256 + t], s);
        W1pt[t * 128 + b] = f2bf(s);
    } else if (b < 384) {
        int idx = (b - 128) * 256 + t;     // W0: K=512, N=128
        int k = idx >> 7, n = idx & 127;
        W0t[n * 512 + k] = f2bf(W0[idx]);
    } else {
        int idx = (b - 384) * 256 + t;     // Wp2: K=256, N=128
        int k = idx >> 7, n = idx & 127;
        Wp2t[n * 256 + k] = f2bf(Wp2[idx]);
    }
}

// ---------------- fused GEMM1 (feat@W0 -> bf16) + atomic-free CSR fill ----------------
__global__ __launch_bounds__(512) void k_gemm1_fill(
    const float* __restrict__ Af, const unsigned short* __restrict__ BH,
    unsigned short* __restrict__ OHs,
    const int* __restrict__ src, const int* __restrict__ dst,
    const int* __restrict__ rowoff, const int* __restrict__ pos,
    int* __restrict__ eidx)
{
    if (blockIdx.x >= GX) {   // ---- fill path (no atomics) ----
        int e = (blockIdx.x - GX) * 512 + threadIdx.x;
        if (e < NE) {
            int d = dst[e];
            eidx[rowoff[d] + pos[e]] = src[e];
        }
        return;
    }
    // ---- GEMM path (K=512, NCOLS=128) ----
    constexpr int K = 512, NCOLS = 128;
    __shared__ __align__(16) unsigned short lds[2 * 4096];
    unsigned short* ldsA = lds;
    unsigned short* ldsB = lds + 4096;

    const int tid  = threadIdx.x;
    const int lane = tid & 63;
    const int wid  = tid >> 6;
    const int wm   = wid >> 1;
    const int wn   = wid & 1;
    const int row0 = blockIdx.x * 128;

    const int srow  = tid >> 2;
    const int skg   = tid & 3;
    const int skswz = skg ^ ((srow >> 1) & 3);
    const size_t aSrc = (size_t)(row0 + srow) * K + skswz * 8;
    const size_t bSrc = (size_t)srow * K + skswz * 8;

    const int frow = lane & 15;
    const int fkg  = lane >> 4;

    f32x4 acc[2][4] = {};

    for (int k0 = 0; k0 < K; k0 += 32) {
        float4 f0, f1;
        if (row0 + srow < NN) {
            const float* ap = Af + aSrc + k0;
            f0 = *reinterpret_cast<const float4*>(ap);
            f1 = *reinterpret_cast<const float4*>(ap + 4);
        } else {
            f0 = make_float4(0.f, 0.f, 0.f, 0.f);
            f1 = f0;
        }
        uint4 w;
        w.x = (unsigned)f2bf(f0.x) | ((unsigned)f2bf(f0.y) << 16);
        w.y = (unsigned)f2bf(f0.z) | ((unsigned)f2bf(f0.w) << 16);
        w.z = (unsigned)f2bf(f1.x) | ((unsigned)f2bf(f1.y) << 16);
        w.w = (unsigned)f2bf(f1.z) | ((unsigned)f2bf(f1.w) << 16);
        *reinterpret_cast<uint4*>(&ldsA[tid * 8]) = w;
        gload16(BH + bSrc + k0, ldsB + tid * 8);
        __syncthreads();

        bf16x8 a_h[2], b_h[4];
#pragma unroll
        for (int mi = 0; mi < 2; ++mi) {
            int ar  = wm * 32 + mi * 16 + frow;
            int idx = ar * 32 + ((fkg ^ ((ar >> 1) & 3)) * 8);
            a_h[mi] = *reinterpret_cast<const bf16x8*>(&ldsA[idx]);
        }
#pragma unroll
        for (int ni = 0; ni < 4; ++ni) {
            int bc  = wn * 64 + ni * 16 + frow;
            int idx = bc * 32 + ((fkg ^ ((bc >> 1) & 3)) * 8);
            b_h[ni] = *reinterpret_cast<const bf16x8*>(&ldsB[idx]);
        }
#pragma unroll
        for (int mi = 0; mi < 2; ++mi)
#pragma unroll
            for (int ni = 0; ni < 4; ++ni)
                acc[mi][ni] = __builtin_amdgcn_mfma_f32_16x16x32_bf16(a_h[mi], b_h[ni], acc[mi][ni], 0, 0, 0);
        __syncthreads();
    }

#pragma unroll
    for (int mi = 0; mi < 2; ++mi) {
        int rbase = row0 + wm * 32 + mi * 16 + (lane >> 4) * 4;
#pragma unroll
        for (int ni = 0; ni < 4; ++ni) {
            int col = wn * 64 + ni * 16 + (lane & 15);
#pragma unroll
            for (int r = 0; r < 4; ++r)
                OHs[(size_t)(rbase + r) * NCOLS + col] = f2bf(acc[mi][ni][r]);
        }
    }
}

// ---------------- single-bf16 MFMA GEMM (flat layouts) ----------------
// AMODE: 0 = bf16 via global_load_lds; 2 = bf16 reg-staged + BN+ReLU (LDS-precomputed).
// OMODE: 0 = fp32 C (rows<NN); 1 = bf16 all rows. STATS: column sum/sumsq (rows<NN).
template <int K, int NCOLS, bool BIAS, int AMODE, int OMODE, bool STATS>
__global__ __launch_bounds__(512) void k_mfma(
    const unsigned short* __restrict__ AH, const unsigned short* __restrict__ BH,
    const float* __restrict__ bias,
    const float* __restrict__ stats, const float* __restrict__ gamma,
    const float* __restrict__ beta,
    float* __restrict__ C, unsigned short* __restrict__ OHs,
    float* __restrict__ statsOut)
{
    __shared__ __align__(16) unsigned short lds[2 * 4096];
    unsigned short* ldsA = lds;
    unsigned short* ldsB = lds + 4096;

    const int tid  = threadIdx.x;
    const int lane = tid & 63;
    const int wid  = tid >> 6;
    const int wm   = wid >> 1;
    const int wn   = wid & 1;
    const int row0 = blockIdx.x * 128;
    const int col0 = blockIdx.y * 128;

    const int srow  = tid >> 2;
    const int skg   = tid & 3;
    const int skswz = skg ^ ((srow >> 1) & 3);
    const size_t aSrc = (size_t)(row0 + srow) * K + skswz * 8;
    const size_t bSrc = (size_t)(col0 + srow) * K + skswz * 8;

    const int frow = lane & 15;
    const int fkg  = lane >> 4;

    __shared__ float s_scl[256], s_shf[256];
    if constexpr (AMODE == 2) {
        if (tid < K) {
            float mu  = stats[tid] * (1.0f / NN);
            float var = stats[256 + tid] * (1.0f / NN) - mu * mu;
            float s = gamma[tid] * rsqrtf(var + 1e-5f);
            s_scl[tid] = s;
            s_shf[tid] = beta[tid] - mu * s;
        }
        __syncthreads();
    }

    f32x4 acc[2][4] = {};

    for (int k0 = 0; k0 < K; k0 += 32) {
        if constexpr (AMODE == 2) {
            uint4 raw = *reinterpret_cast<const uint4*>(&AH[aSrc + k0]);
            unsigned rw[4] = {raw.x, raw.y, raw.z, raw.w};
            int kc = k0 + skswz * 8;
            float vv[8];
#pragma unroll
            for (int q = 0; q < 8; ++q) {
                float z = bf2f((unsigned short)((q & 1) ? (rw[q >> 1] >> 16)
                                                        : (rw[q >> 1] & 0xFFFF)));
                vv[q] = fmaxf(fmaf(z, s_scl[kc + q], s_shf[kc + q]), 0.f);
            }
            uint4 w;
            w.x = (unsigned)f2bf(vv[0]) | ((unsigned)f2bf(vv[1]) << 16);
            w.y = (unsigned)f2bf(vv[2]) | ((unsigned)f2bf(vv[3]) << 16);
            w.z = (unsigned)f2bf(vv[4]) | ((unsigned)f2bf(vv[5]) << 16);
            w.w = (unsigned)f2bf(vv[6]) | ((unsigned)f2bf(vv[7]) << 16);
            *reinterpret_cast<uint4*>(&ldsA[tid * 8]) = w;
        } else {
            gload16(AH + aSrc + k0, ldsA + tid * 8);
        }
        gload16(BH + bSrc + k0, ldsB + tid * 8);
        __syncthreads();

        bf16x8 a_h[2], b_h[4];
#pragma unroll
        for (int mi = 0; mi < 2; ++mi) {
            int ar  = wm * 32 + mi * 16 + frow;
            int idx = ar * 32 + ((fkg ^ ((ar >> 1) & 3)) * 8);
            a_h[mi] = *reinterpret_cast<const bf16x8*>(&ldsA[idx]);
        }
#pragma unroll
        for (int ni = 0; ni < 4; ++ni) {
            int bc  = wn * 64 + ni * 16 + frow;
            int idx = bc * 32 + ((fkg ^ ((bc >> 1) & 3)) * 8);
            b_h[ni] = *reinterpret_cast<const bf16x8*>(&ldsB[idx]);
        }
#pragma unroll
        for (int mi = 0; mi < 2; ++mi)
#pragma unroll
            for (int ni = 0; ni < 4; ++ni)
                acc[mi][ni] = __builtin_amdgcn_mfma_f32_16x16x32_bf16(a_h[mi], b_h[ni], acc[mi][ni], 0, 0, 0);
        __syncthreads();
    }

    float psum[4] = {0.f, 0.f, 0.f, 0.f}, psq[4] = {0.f, 0.f, 0.f, 0.f};
#pragma unroll
    for (int mi = 0; mi < 2; ++mi) {
        int rbase = row0 + wm * 32 + mi * 16 + (lane >> 4) * 4;
#pragma unroll
        for (int ni = 0; ni < 4; ++ni) {
            int col = col0 + wn * 64 + ni * 16 + (lane & 15);
            float b = BIAS ? bias[col] : 0.f;
#pragma unroll
            for (int r = 0; r < 4; ++r) {
                int row = rbase + r;
                float v = acc[mi][ni][r] + b;
                if constexpr (STATS) {
                    if (row < NN) { psum[ni] += v; psq[ni] = fmaf(v, v, psq[ni]); }
                }
                if constexpr (OMODE == 1) {
                    OHs[(size_t)row * NCOLS + col] = f2bf(v);   // pad rows too
                } else {
                    if (row < NN) C[(size_t)row * NCOLS + col] = v;
                }
            }
        }
    }

    if constexpr (STATS) {
        __shared__ float s_sum[128], s_sq[128];
        if (tid < 128) { s_sum[tid] = 0.f; s_sq[tid] = 0.f; }
        __syncthreads();
#pragma unroll
        for (int ni = 0; ni < 4; ++ni) {
            float a = psum[ni], q = psq[ni];
            a += __shfl_xor(a, 16); a += __shfl_xor(a, 32);
            q += __shfl_xor(q, 16); q += __shfl_xor(q, 32);
            if ((lane >> 4) == 0) {
                int cl = wn * 64 + ni * 16 + lane;
                atomicAdd(&s_sum[cl], a);
                atomicAdd(&s_sq[cl], q);
            }
        }
        __syncthreads();
        if (tid < 128) {
            atomicAdd(&statsOut[col0 + tid], s_sum[tid]);
            atomicAdd(&statsOut[256 + col0 + tid], s_sq[tid]);
        }
    }
}

extern "C" void kernel_launch(void* const* d_in, const int* in_sizes, int n_in,
                              void* d_out, int out_size, void* d_ws, size_t ws_size,
                              hipStream_t stream) {
    const float* feat  = (const float*)d_in[0];
    const int*   src   = (const int*)d_in[1];
    const int*   dst   = (const int*)d_in[2];
    const float* W0    = (const float*)d_in[3];
    const float* W1    = (const float*)d_in[4];
    const float* Wp1   = (const float*)d_in[5];
    const float* bp1   = (const float*)d_in[6];
    const float* gamma = (const float*)d_in[7];
    const float* beta  = (const float*)d_in[8];
    const float* Wp2   = (const float*)d_in[9];
    const float* bp2   = (const float*)d_in[10];
    float* out = (float*)d_out;

    char* wsb = (char*)d_ws;
    float* dinv   = (float*)(wsb + 4ull * 0);          // 50048
    int*   cnt    = (int*)  (wsb + 4ull * 50048);      // 50048
    int*   rowoff = (int*)  (wsb + 4ull * 100096);     // 50048
    int*   bsum   = (int*)  (wsb + 4ull * 150144);     // 256
    int*   boff   = (int*)  (wsb + 4ull * 150400);     // 256
    int*   pos    = (int*)  (wsb + 4ull * 150656);     // 800000
    int*   eidx   = (int*)  (wsb + 4ull * 950656);     // 800000
    float* stats  = (float*)(wsb + 4ull * 1750656);    // 512
    unsigned short* W0t  = (unsigned short*)(wsb + 4ull * 1751168);   // 65536 u16
    unsigned short* W1pt = W0t + 65536;                               // 32768 u16
    unsigned short* Wp2t = W1pt + 32768;                              // 32768 u16
    unsigned short* H0 = (unsigned short*)(wsb + 4ull * 1816704);     // [NNP][128] u16
    unsigned short* h1 = (unsigned short*)(wsb + 4ull * 5019776);
    unsigned short* h2 = H0;   // reuse after H0 consumed
    unsigned short* ZH = (unsigned short*)(wsb + 4ull * 8222848);     // [NNP][256] u16

    // ---- CSR build (count+slot assignment fused into wprep) ----
    hipMemsetAsync(cnt, 0, 50048 * sizeof(int), stream);
    k_wprep_count<<<512 + (NE + 255) / 256, 256, 0, stream>>>(
        W0, W1, Wp1, Wp2, W0t, W1pt, Wp2t, stats, dst, cnt, pos);
    k_bsum<<<NB, 256, 0, stream>>>(cnt, bsum);
    k_scan_bsum<<<1, 256, 0, stream>>>(bsum, boff);
    k_scan_block<<<NB, 256, 0, stream>>>(cnt, boff, rowoff, dinv);

    // H0 = feat @ W0 (bf16 out) FUSED with atomic-free CSR eidx fill
    k_gemm1_fill<<<GX + FILLB, 512, 0, stream>>>(
        feat, W0t, H0, src, dst, rowoff, pos, eidx);

    // h1 = conv(H0); h2 = conv(h1)   [conv commutes with right-mult by W]
    k_gather_shfl<<<NNP / 4, 256, 0, stream>>>(H0, dinv, rowoff, cnt, eidx, h1);
    k_gather_shfl<<<NNP / 4, 256, 0, stream>>>(h1, dinv, rowoff, cnt, eidx, h2);

    // Z = h2 @ (W1@Wp1) + bp1  [NNP,256] bf16, fused BN column stats
    k_mfma<128, 256, true, 0, 1, true><<<dim3(GX, 2), 512, 0, stream>>>(
        h2, W1pt, bp1, nullptr, nullptr, nullptr, nullptr, ZH, stats);

    // out = relu(BN(Z)) @ Wp2 + bp2  (BN scale/shift precomputed per block in LDS)
    k_mfma<256, 128, true, 2, 0, false><<<dim3(GX, 1), 512, 0, stream>>>(
        ZH, Wp2t, bp2, stats, gamma, beta, out, nullptr, nullptr);
}